// Round 15
// baseline (576.894 us; speedup 1.0000x reference)
//
#include <hip/hip_runtime.h>
#include <hip/hip_bf16.h>

typedef __bf16 bf16;
typedef bf16 bf16x4 __attribute__((ext_vector_type(4)));
typedef bf16 bf16x8 __attribute__((ext_vector_type(8)));
typedef float f32x4 __attribute__((ext_vector_type(4)));

constexpr int SEQ  = 2048;
constexpr int BAT  = 4;
constexpr int NH   = 8;
constexpr int NTOK = SEQ * BAT;   // 8192
constexpr int QKVW = 1792;        // fused projection width: 512+512+512+256
constexpr size_t MB = 1ull << 20;

// ---------------------------------------------------------------------------
// async global->LDS 16B copy (wave-uniform LDS base + lane*16, m104)
// ---------------------------------------------------------------------------
__device__ inline void async_lds16(const void* g, void* l) {
  __builtin_amdgcn_global_load_lds(
      (__attribute__((address_space(1))) void*)(g),
      (__attribute__((address_space(3))) void*)(l), 16, 0, 0);
}

#define MFMA16 __builtin_amdgcn_mfma_f32_16x16x32_bf16

// ---------------------------------------------------------------------------
// Fused attention (round-15 = round-14 + Q-in-regs + exp2 + QK setprio).
// Block = (qb, h, b, vh): 64 Q-rows x 256 V-cols (4 rules), KVBLK=128.
// 2 blocks/CU (vh split, 32-AGPR acc). Q frags held in 32 VGPRs (96 total,
// fits the 128/wave cap at 4 waves/SIMD). Logits are base-2 (scale folded
// into Wq/bq) so exp2f -> single v_exp_f32.
// ---------------------------------------------------------------------------
__global__ __launch_bounds__(512, 4)
void attn_kernel(const bf16* __restrict__ qkv, const bf16* __restrict__ vT,
                 bf16* __restrict__ outb) {
  __shared__ __align__(16) bf16 Qs[64 * 64];        // 8 KB
  __shared__ __align__(16) bf16 Ks[2][128 * 64];    // 32 KB
  __shared__ __align__(16) bf16 Ps[2][64 * 128];    // 32 KB (step-parity dbuf)
  __shared__ float rsAll[8][64];
  __shared__ float rsInv[64];

  const int tid = threadIdx.x;
  const int lane = tid & 63, w = tid >> 6;
  const int r16 = lane & 15, rq = lane >> 4;

  // bijective XCD-chunked decode (nwg = 2048 = 8 * 256):
  // each XCD owns one (b, vh) slice -> K+V working set ~2 MB, L2-resident.
  const int flat = blockIdx.x + 32 * (blockIdx.y + 8 * blockIdx.z);
  const int swz = (flat & 7) * 256 + (flat >> 3);
  const int qb = swz & 31, h = (swz >> 5) & 7;
  const int zz = swz >> 8, b = zz >> 1, vh = zz & 1;

  // ---- stage Q tile [64 rows][64 d] (head h = q cols h*64..) ----
  const bf16* qbase = qkv + ((long)b * SEQ + qb * 64) * QKVW + h * 64;
  {
    const int rr = tid >> 3, sl = tid & 7;
    async_lds16(qbase + (long)rr * QKVW + ((sl ^ (rr & 7)) << 3),
                Qs + (size_t)w * 512);                 // wave-uniform base
  }
  // ---- K staging [128 rows][64 d], 2 chunks/thread ----
  const bf16* kbase = qkv + (long)b * SEQ * QKVW + 512 + h * 64;
  auto stageK = [&](int buf, int t0) {
#pragma unroll
    for (int g = 0; g < 2; g++) {
      const int c = g * 512 + tid;                   // lane-contiguous
      const int rr = c >> 3, sl = c & 7;
      async_lds16(kbase + (long)(t0 + rr) * QKVW + ((sl ^ (rr & 7)) << 3),
                  Ks[buf] + (size_t)(g * 8 + w) * 512);
    }
  };
  // per-lane V row pointers: this block's cols = vh*256 + w*32 + n*16 + r16
  const bf16* vp[2];
#pragma unroll
  for (int n = 0; n < 2; n++)
    vp[n] = vT + ((long)b * 512 + vh * 256 + w * 32 + n * 16 + r16) * SEQ + rq * 8;

  f32x4 acc[4][2] = {};   // [m-frag][n-frag] -> 32 AGPR
  float rs[4] = {};       // row-sum partials (per j)

  stageK(0, 0);
  asm volatile("s_waitcnt vmcnt(0)" ::: "memory");
  __builtin_amdgcn_s_barrier();
  __builtin_amdgcn_sched_barrier(0);

  // Q b-frags held in regs for whole kernel (32 VGPR)
  bf16x8 qf[4][2];
#pragma unroll
  for (int j = 0; j < 4; j++)
#pragma unroll
    for (int kf = 0; kf < 2; kf++) {
      const int row = j * 16 + r16;
      qf[j][kf] = *(const bf16x8*)&Qs[row * 64 + (((kf * 4 + rq) ^ (row & 7)) << 3)];
    }

  const int krow = w * 16 + r16;              // this wave's key row (16 keys)
  for (int t = 0; t < 16; ++t) {
    const int t0 = t * 128;
    // ---- V groups 0,1 issued FIRST ----
    bf16x8 v0[2], v1[2];
#pragma unroll
    for (int n = 0; n < 2; n++) v0[n] = *(const bf16x8*)(vp[n] + t0);
#pragma unroll
    for (int n = 0; n < 2; n++) v1[n] = *(const bf16x8*)(vp[n] + t0 + 32);
    __builtin_amdgcn_sched_barrier(0);
    if (t < 15) {
      stageK((t + 1) & 1, t0 + 128);        // K(t+1) prefetch
      __builtin_amdgcn_sched_barrier(0);
      asm volatile("s_waitcnt vmcnt(8)" ::: "memory");   // K(t) resident
    } else {
      asm volatile("s_waitcnt vmcnt(4)" ::: "memory");
    }
    __builtin_amdgcn_s_barrier();            // K(t) visible to all waves
    __builtin_amdgcn_sched_barrier(0);
    // ---- QK^T (swapped: S^T[key][qrow]), Q from regs ----
    bf16x8 kfr[2];
#pragma unroll
    for (int kf = 0; kf < 2; kf++)
      kfr[kf] = *(const bf16x8*)&Ks[t & 1][krow * 64 + (((kf * 4 + rq) ^ (krow & 7)) << 3)];
    f32x4 s4[4] = {};
    __builtin_amdgcn_s_setprio(1);
#pragma unroll
    for (int j = 0; j < 4; j++) {
      s4[j] = MFMA16(kfr[0], qf[j][0], s4[j], 0, 0, 0);
      s4[j] = MFMA16(kfr[1], qf[j][1], s4[j], 0, 0, 0);
    }
    __builtin_amdgcn_s_setprio(0);
    // ---- exp2 + row-sum + pack P (logits are base-2: scale folded) ----
    bf16* Pcur = Ps[t & 1];
#pragma unroll
    for (int j = 0; j < 4; j++) {
      const float e0 = exp2f(s4[j][0]), e1 = exp2f(s4[j][1]);
      const float e2 = exp2f(s4[j][2]), e3 = exp2f(s4[j][3]);
      rs[j] += (e0 + e1) + (e2 + e3);
      bf16x4 pk; pk[0] = (bf16)e0; pk[1] = (bf16)e1; pk[2] = (bf16)e2; pk[3] = (bf16)e3;
      const int row = j * 16 + r16;
      *(bf16x4*)&Pcur[row * 128 + (((w * 2 + (rq >> 1)) ^ (row & 7)) << 3) + ((rq & 1) << 2)] = pk;
    }
    asm volatile("s_waitcnt lgkmcnt(0)" ::: "memory");   // P writes drained
    __builtin_amdgcn_s_barrier();            // P(t) ready
    __builtin_amdgcn_sched_barrier(0);
    // ---- PV: acc += P[64 x 128] @ V[128 x 32(wave)], rolling V prefetch ----
#pragma unroll
    for (int g = 0; g < 4; g++) {
      bf16x8 v2[2];
      if (g < 2) {
#pragma unroll
        for (int n = 0; n < 2; n++)
          v2[n] = *(const bf16x8*)(vp[n] + t0 + (g + 2) * 32);
      }
      bf16x8 pf[4];
#pragma unroll
      for (int i = 0; i < 4; i++) {
        const int row = i * 16 + r16;
        pf[i] = *(const bf16x8*)&Ps[t & 1][row * 128 + (((rq + g * 4) ^ (row & 7)) << 3)];
      }
      __builtin_amdgcn_s_setprio(1);
#pragma unroll
      for (int i = 0; i < 4; i++) {
        acc[i][0] = MFMA16(pf[i], v0[0], acc[i][0], 0, 0, 0);
        acc[i][1] = MFMA16(pf[i], v0[1], acc[i][1], 0, 0, 0);
      }
      __builtin_amdgcn_s_setprio(0);
#pragma unroll
      for (int n = 0; n < 2; n++) { v0[n] = v1[n]; v1[n] = v2[n]; }  // renamed
    }
    // no end-of-step barrier: P step-dbuf'd (WAR is 2 barriers away)
  }

  // ---- epilogue: row-sum reduce (rq lanes -> waves) + normalize + store ----
#pragma unroll
  for (int j = 0; j < 4; j++) {
    rs[j] += __shfl_xor(rs[j], 16);
    rs[j] += __shfl_xor(rs[j], 32);
  }
  if (rq == 0) {
#pragma unroll
    for (int j = 0; j < 4; j++) rsAll[w][j * 16 + r16] = rs[j];
  }
  asm volatile("s_waitcnt lgkmcnt(0)" ::: "memory");
  __builtin_amdgcn_s_barrier();
  if (tid < 64) {
    float tot = 0.f;
#pragma unroll
    for (int u = 0; u < 8; u++) tot += rsAll[u][tid];
    rsInv[tid] = 1.f / tot;
  }
  asm volatile("s_waitcnt lgkmcnt(0)" ::: "memory");
  __builtin_amdgcn_s_barrier();

  bf16* obase = outb + (((long)(b * NH + h) * SEQ) + qb * 64) * 512 + vh * 256 + w * 32;
#pragma unroll
  for (int i = 0; i < 4; i++) {
#pragma unroll
    for (int rg = 0; rg < 4; rg++) {
      const int row = i * 16 + rq * 4 + rg;
      const float inv = rsInv[row];
#pragma unroll
      for (int n = 0; n < 2; n++)
        obase[(long)row * 512 + n * 16 + r16] = (bf16)(acc[i][n][rg] * inv);
    }
  }
}

// ---------------------------------------------------------------------------
// bf16 MFMA GEMM, 128x128 tile, BK=32, 4 waves, 3-deep counted-vmcnt pipeline
// (T3+T4) + T1 XCD-chunked block swizzle + T5 setprio.  [round-4 proven loop]
// bias applied only on the z==0 slice. flags: bit0 = bf16 out, bit1 = relu.
// Split-K: sAz/sBz = per-z K-offsets (elements), sCz = partial-buffer stride.
// ---------------------------------------------------------------------------
__global__ __launch_bounds__(256)
void gemm_bt(const bf16* __restrict__ A, const bf16* __restrict__ B,
             void* __restrict__ C, const float* __restrict__ bias,
             int K, int lda, int ldb, int ldc,
             long sAz, long sBz, long sCz,
             float scale, int flags) {
  constexpr int LPT = 4;
  __shared__ __align__(16) bf16 As[3][128 * 32];
  __shared__ __align__(16) bf16 Bs[3][128 * 32];

  const int tid  = threadIdx.x;
  const int lane = tid & 63;
  const int w    = tid >> 6;
  const int wr   = w >> 1, wc = w & 1;

  const int gx = gridDim.x, gy = gridDim.y;
  const int nwg = gx * gy * gridDim.z;
  const int flat = blockIdx.x + gx * (blockIdx.y + gy * blockIdx.z);
  const int q = nwg >> 3, r = nwg & 7;
  const int xcd = flat & 7, pos = flat >> 3;
  int swz = (xcd < r ? xcd * (q + 1) : r * (q + 1) + (xcd - r) * q) + pos;
  const int bx = swz % gx; swz /= gx;
  const int by = swz % gy;
  const long z = swz / gy;

  const bf16* Ab = A + (long)by * 128 * lda + z * sAz;
  const bf16* Bb = B + (long)bx * 128 * ldb + z * sBz;

  const bf16* aSrc[2];
  const bf16* bSrc[2];
#pragma unroll
  for (int g = 0; g < 2; g++) {
    const int c = (w * 2 + g) * 64 + lane;
    const int rr = c >> 2, sl = c & 3;
    aSrc[g] = Ab + (long)rr * lda + ((sl ^ ((rr >> 1) & 3)) << 3);
    bSrc[g] = Bb + (long)rr * ldb + ((sl ^ ((rr >> 1) & 3)) << 3);
  }

  f32x4 acc[4][4] = {};
  const int r16 = lane & 15, kq = lane >> 4;
  const int so = ((kq ^ ((r16 >> 1) & 3)) << 3);

  auto stage = [&](int buf, int k0) {
#pragma unroll
    for (int g = 0; g < 2; g++)
      async_lds16(aSrc[g] + k0, &As[buf][(w * 2 + g) * 512]);
#pragma unroll
    for (int g = 0; g < 2; g++)
      async_lds16(bSrc[g] + k0, &Bs[buf][(w * 2 + g) * 512]);
  };
  bf16x8 areg[4], breg[4];
  auto loadfrags = [&](int buf) {
#pragma unroll
    for (int i = 0; i < 4; i++)
      areg[i] = *(const bf16x8*)&As[buf][(wr * 64 + i * 16 + r16) * 32 + so];
#pragma unroll
    for (int j = 0; j < 4; j++)
      breg[j] = *(const bf16x8*)&Bs[buf][(wc * 64 + j * 16 + r16) * 32 + so];
  };
  auto domfma = [&]() {
    __builtin_amdgcn_s_setprio(1);
#pragma unroll
    for (int i = 0; i < 4; i++)
#pragma unroll
      for (int j = 0; j < 4; j++)
        acc[i][j] = MFMA16(areg[i], breg[j], acc[i][j], 0, 0, 0);
    __builtin_amdgcn_s_setprio(0);
  };

  const int nt = K >> 5;
  stage(0, 0);
  if (nt > 1) stage(1, 32);

  int cs = 2, cc = 0;
  for (int t = 0; t + 2 < nt; ++t) {
    stage(cs, (t + 2) * 32);
    asm volatile("s_waitcnt vmcnt(%0)" : : "n"(2 * LPT) : "memory");
    __builtin_amdgcn_s_barrier();
    loadfrags(cc);
    asm volatile("s_waitcnt lgkmcnt(0)" : : : "memory");
    __builtin_amdgcn_sched_barrier(0);
    __builtin_amdgcn_s_barrier();
    domfma();
    if (++cs == 3) cs = 0;
    if (++cc == 3) cc = 0;
  }
  if (nt >= 2) {
    asm volatile("s_waitcnt vmcnt(%0)" : : "n"(LPT) : "memory");
    __builtin_amdgcn_s_barrier();
    loadfrags(cc);
    asm volatile("s_waitcnt lgkmcnt(0)" : : : "memory");
    __builtin_amdgcn_sched_barrier(0);
    domfma();
    if (++cc == 3) cc = 0;
  }
  asm volatile("s_waitcnt vmcnt(0)" : : : "memory");
  __builtin_amdgcn_s_barrier();
  loadfrags(cc);
  domfma();

  const long rowBase = (long)by * 128 + wr * 64;
  const int  colBase = bx * 128 + wc * 64;
  float* Cf = (float*)C;
  bf16*  Cb = (bf16*)C;
  const int rq = lane >> 4;
#pragma unroll
  for (int i = 0; i < 4; i++) {
#pragma unroll
    for (int j = 0; j < 4; j++) {
      const int col = colBase + j * 16 + r16;
      const float bv = (bias && z == 0) ? bias[col] : 0.f;
#pragma unroll
      for (int rg = 0; rg < 4; rg++) {
        const long row = rowBase + i * 16 + rq * 4 + rg;
        float y = (acc[i][j][rg] + bv) * scale;
        if (flags & 2) y = fmaxf(y, 0.f);
        const long idx = z * sCz + row * (long)ldc + col;
        if (flags & 1) Cb[idx] = (bf16)y;
        else           Cf[idx] = y;
      }
    }
  }
}

// ---------------------------------------------------------------------------
__global__ void transpose_w_kernel(const float* __restrict__ in, bf16* __restrict__ out,
                                   int K, int N, float scale) {
  __shared__ float t[32][33];
  const int n0 = blockIdx.x * 32, k0 = blockIdx.y * 32;
  const int tx = threadIdx.x, ty = threadIdx.y;
#pragma unroll
  for (int i = ty; i < 32; i += 8)
    t[i][tx] = in[(long)(k0 + i) * N + n0 + tx];
  __syncthreads();
#pragma unroll
  for (int i = ty; i < 32; i += 8)
    out[(long)(n0 + i) * K + k0 + tx] = (bf16)(t[tx][i] * scale);
}

__global__ void build_bias_kernel(const float* bq, const float* bk,
                                  const float* bv, const float* bqv,
                                  float* __restrict__ out) {
  const int i = blockIdx.x * 256 + threadIdx.x;
  float v;
  if (i < 512)       v = bq[i] * 0.18033688011112042f;   // 0.125 * log2(e)
  else if (i < 1024) v = bk[i - 512];
  else if (i < 1536) v = bv[i - 1024];
  else               v = bqv[i - 1536] * 0.17677669529663687f;
  out[i] = v;
}

// v (cols 1024..1535 of qkv) -> vT bf16 [B][512][S]
__global__ void transpose_v_kernel(const bf16* __restrict__ qkv, bf16* __restrict__ vT) {
  __shared__ bf16 t[32][33];
  const int s0 = blockIdx.x * 32, c0 = blockIdx.y * 32, b = blockIdx.z;
  const int tx = threadIdx.x, ty = threadIdx.y;
#pragma unroll
  for (int i = ty; i < 32; i += 8)
    t[i][tx] = qkv[((long)b * SEQ + s0 + i) * QKVW + 1024 + c0 + tx];
  __syncthreads();
#pragma unroll
  for (int i = ty; i < 32; i += 8)
    vT[(long)b * 512 * SEQ + (long)(c0 + i) * SEQ + s0 + tx] = t[tx][i];
}

// x f32 [S][B][D] -> xb bf16 [B*S][D]
__global__ __launch_bounds__(256)
void convert_x_kernel(const float* __restrict__ x, bf16* __restrict__ xb) {
  const long i0 = ((long)blockIdx.x * 256 + threadIdx.x) * 8;
  const int t = (int)(i0 >> 9), d = (int)(i0 & 511);
  const int b = t >> 11, s = t & 2047;
  const float* src = x + ((long)(s * BAT + b) << 9) + d;
  const float4 f0 = *(const float4*)(src);
  const float4 f1 = *(const float4*)(src + 4);
  bf16x8 o;
  o[0] = (bf16)f0.x; o[1] = (bf16)f0.y; o[2] = (bf16)f0.z; o[3] = (bf16)f0.w;
  o[4] = (bf16)f1.x; o[5] = (bf16)f1.y; o[6] = (bf16)f1.z; o[7] = (bf16)f1.w;
  *(bf16x8*)&xb[i0] = o;
}

// ---------------------------------------------------------------------------
// Stage-2 composition: one wave per (b,h,s).
// ---------------------------------------------------------------------------
__global__ __launch_bounds__(256)
void stage2_kernel(const bf16* __restrict__ outbuf, long strideB,
                   const bf16* __restrict__ qvb, int qvStride,
                   const float* __restrict__ Wkv,
                   const float* __restrict__ bkv,
                   bf16* __restrict__ attn) {
  const int lane = threadIdx.x & 63, wid = threadIdx.x >> 6;
  const int g = blockIdx.x * 4 + wid;
  const int s = g & 2047, h = (g >> 11) & 7, b = g >> 14;
  const int token = b * SEQ + s;

  const bf16* qv = qvb + (long)token * qvStride + h * 32;
  const float* wrow = Wkv + lane * 32;
  float wq = 0.f, cb = 0.f;
#pragma unroll 8
  for (int q = 0; q < 32; q++) {
    const float qf = (float)qv[q];
    wq += wrow[q] * qf;
    cb += bkv[q] * qf;
  }

  const bf16* orow = outbuf + b * strideB + ((long)(h << 11) + s) * 512;
  float of[8], lg[8];
#pragma unroll
  for (int r = 0; r < 8; r++) {
    of[r] = (float)orow[r * 64 + lane];
    float p = of[r] * wq;
    for (int o = 1; o < 64; o <<= 1) p += __shfl_xor(p, o);
    lg[r] = p + cb;
  }
  float m = lg[0];
#pragma unroll
  for (int r = 1; r < 8; r++) m = fmaxf(m, lg[r]);
  float e[8], sum = 0.f;
#pragma unroll
  for (int r = 0; r < 8; r++) { e[r] = __expf(lg[r] - m); sum += e[r]; }
  const float inv = 1.f / sum;
  float o = 0.f;
#pragma unroll
  for (int r = 0; r < 8; r++) o += e[r] * inv * of[r];
  attn[(long)token * 512 + h * 64 + lane] = (bf16)o;
}

// ---------------------------------------------------------------------------
// LayerNorm over D=512 per token; optional split-K partial at +part2 elems.
// ---------------------------------------------------------------------------
__global__ __launch_bounds__(256)
void ln_kernel(const float* __restrict__ a, long part2,
               const float* __restrict__ bres, int bresT,
               const float* __restrict__ g, const float* __restrict__ be,
               float* __restrict__ outF, bf16* __restrict__ outB, int outT) {
  __shared__ float red[8];
  const int t = blockIdx.x, tid = threadIdx.x;
  const int b = t >> 11, s = t & 2047;
  const long ti = (long)t * 512;
  const long xi = (long)(s * BAT + b) * 512;
  const long ri = bresT ? xi : ti;
  float v0 = a[ti + tid]       + bres[ri + tid];
  float v1 = a[ti + 256 + tid] + bres[ri + 256 + tid];
  if (part2) { v0 += a[part2 + ti + tid]; v1 += a[part2 + ti + 256 + tid]; }
  float sum = v0 + v1, sq = v0 * v0 + v1 * v1;
  const int lane = tid & 63, wid = tid >> 6;
  for (int o = 1; o < 64; o <<= 1) { sum += __shfl_xor(sum, o); sq += __shfl_xor(sq, o); }
  if (lane == 0) { red[wid] = sum; red[4 + wid] = sq; }
  __syncthreads();
  sum = red[0] + red[1] + red[2] + red[3];
  sq  = red[4] + red[5] + red[6] + red[7];
  const float mu = sum * (1.f / 512.f);
  const float var = sq * (1.f / 512.f) - mu * mu;
  const float rs = rsqrtf(var + 1e-5f);
  const float y0 = (v0 - mu) * rs * g[tid] + be[tid];
  const float y1 = (v1 - mu) * rs * g[tid + 256] + be[tid + 256];
  const long oi = outT ? xi : ti;
  if (outF) { outF[oi + tid] = y0; outF[oi + 256 + tid] = y1; }
  if (outB) { outB[ti + tid] = (bf16)y0; outB[ti + 256 + tid] = (bf16)y1; }
}

// ---------------------------------------------------------------------------
extern "C" void kernel_launch(void* const* d_in, const int* in_sizes, int n_in,
                              void* d_out, int out_size, void* d_ws, size_t ws_size,
                              hipStream_t stream) {
  const float* x   = (const float*)d_in[0];
  const float* Wq  = (const float*)d_in[1];
  const float* bq  = (const float*)d_in[2];
  const float* Wk  = (const float*)d_in[3];
  const float* bk  = (const float*)d_in[4];
  const float* Wv  = (const float*)d_in[5];
  const float* bv  = (const float*)d_in[6];
  const float* Wqv = (const float*)d_in[7];
  const float* bqv = (const float*)d_in[8];
  const float* Wkv = (const float*)d_in[9];
  const float* bkv = (const float*)d_in[10];
  const float* Wf  = (const float*)d_in[11];
  const float* bfc = (const float*)d_in[12];
  const float* W1  = (const float*)d_in[13];
  const float* b1  = (const float*)d_in[14];
  const float* W2  = (const float*)d_in[15];
  const float* b2  = (const float*)d_in[16];
  const float* g1  = (const float*)d_in[17];
  const float* be1 = (const float*)d_in[18];
  const float* g2  = (const float*)d_in[19];
  const float* be2 = (const float*)d_in[20];

  char* ws = (char*)d_ws;
  size_t off = 0;
  auto alloc = [&](size_t bytes) -> void* {
    void* p = ws + off;
    off += (bytes + 1023) & ~(size_t)1023;
    return p;
  };
  // ---- persistent (~50 MB) ----
  bf16*  qkv   = (bf16*)alloc((size_t)NTOK * QKVW * 2);
  bf16*  vT    = (bf16*)alloc((size_t)BAT * 512 * SEQ * 2);
  bf16*  wtPk  = (bf16*)alloc((size_t)QKVW * 512 * 2);
  bf16*  WfT   = (bf16*)alloc(512 * 512 * 2);
  bf16*  W1T   = (bf16*)alloc((size_t)2048 * 512 * 2);
  bf16*  W2T   = (bf16*)alloc((size_t)512 * 2048 * 2);
  float* bcat  = (float*)alloc(QKVW * 4);
  bf16*  attn  = (bf16*)alloc((size_t)NTOK * 512 * 2);

  // ---- shared region (96 MB), phases temporally disjoint ----
  // attn phase: [outb 64]    ffn phase: [xb 8 | wfoP 32 | ln1f 16 | ln1b 8 | ffn1 32]
  char* reg = ws + off;
  bf16*  outb  = (bf16*)reg;                 //  0..64 (dead after stage2)
  bf16*  xb    = (bf16*)reg;                 //  0..8  (dead after projection)
  float* wfoP  = (float*)(reg + 8 * MB);     //  8..40 (2 f32 partials)
  float* ln1f  = (float*)(reg + 40 * MB);    // 40..56
  bf16*  ln1b  = (bf16*)(reg + 56 * MB);     // 56..64
  bf16*  ffn1  = (bf16*)(reg + 64 * MB);     // 64..96

  const dim3 tb(32, 8);
  // q scale folds softmax's 1/sqrt(64) AND log2(e) so attn can use exp2
  transpose_w_kernel<<<dim3(16, 16), tb, 0, stream>>>(Wq,  wtPk,              512, 512, 0.18033688011112042f);
  transpose_w_kernel<<<dim3(16, 16), tb, 0, stream>>>(Wk,  wtPk + 512  * 512, 512, 512, 1.f);
  transpose_w_kernel<<<dim3(16, 16), tb, 0, stream>>>(Wv,  wtPk + 1024 * 512, 512, 512, 1.f);
  transpose_w_kernel<<<dim3(8, 16),  tb, 0, stream>>>(Wqv, wtPk + 1536 * 512, 512, 256, 0.17677669529663687f);
  transpose_w_kernel<<<dim3(16, 16), tb, 0, stream>>>(Wf,  WfT, 512, 512, 1.f);
  transpose_w_kernel<<<dim3(64, 16), tb, 0, stream>>>(W1,  W1T, 512, 2048, 1.f);
  transpose_w_kernel<<<dim3(16, 64), tb, 0, stream>>>(W2,  W2T, 2048, 512, 1.f);
  build_bias_kernel<<<7, 256, 0, stream>>>(bq, bk, bv, bqv, bcat);
  convert_x_kernel<<<2048, 256, 0, stream>>>(x, xb);

  // fused q|k|v|qv projection: [8192,512] @ [1792,512]^T -> [8192,1792]
  gemm_bt<<<dim3(14, 64, 1), 256, 0, stream>>>(xb, wtPk, qkv, bcat,
      512, 512, 512, QKVW, 0, 0, 0, 1.f, 1);

  transpose_v_kernel<<<dim3(64, 16, 4), tb, 0, stream>>>(qkv, vT);

  // fused attention: score+softmax+PV; V-cols split across z (2 blocks/CU)
  attn_kernel<<<dim3(SEQ / 64, NH, BAT * 2), 512, 0, stream>>>(qkv, vT, outb);

  stage2_kernel<<<BAT * NH * SEQ / 4, 256, 0, stream>>>(outb, (long)NH * SEQ * 512,
      qkv + 1536, QKVW, Wkv, bkv, attn);

  const long sWf = (long)NTOK * 512;
  // Wf projection, split-K z=2, f32 partials (bias on z==0), summed by ln1
  gemm_bt<<<dim3(4, 64, 2), 256, 0, stream>>>(attn, WfT, wfoP, bfc,
      256, 512, 512, 512, 256, 256, sWf, 1.f, 0);
  ln_kernel<<<NTOK, 256, 0, stream>>>(wfoP, sWf, x, 1, g1, be1, ln1f, ln1b, 0);
  gemm_bt<<<dim3(16, 64, 1), 256, 0, stream>>>(ln1b, W1T, ffn1, b1,
      512, 512, 512, 2048, 0, 0, 0, 1.f, 1 | 2);
  // ffn2, split-K z=2, f32 partials (bias on z==0), summed by ln2
  gemm_bt<<<dim3(4, 64, 2), 256, 0, stream>>>(ffn1, W2T, wfoP, b2,
      1024, 2048, 2048, 512, 1024, 1024, sWf, 1.f, 0);
  ln_kernel<<<NTOK, 256, 0, stream>>>(wfoP, sWf, ln1f, 0, g2, be2, (float*)d_out, nullptr, 1);
}

// Round 16
// 516.680 us; speedup vs baseline: 1.1165x; 1.1165x over previous
//
#include <hip/hip_runtime.h>
#include <hip/hip_bf16.h>

typedef __bf16 bf16;
typedef bf16 bf16x4 __attribute__((ext_vector_type(4)));
typedef bf16 bf16x8 __attribute__((ext_vector_type(8)));
typedef float f32x4 __attribute__((ext_vector_type(4)));

constexpr int SEQ  = 2048;
constexpr int BAT  = 4;
constexpr int NH   = 8;
constexpr int NTOK = SEQ * BAT;   // 8192
constexpr int QKVW = 1792;        // fused projection width: 512+512+512+256
constexpr size_t MB = 1ull << 20;

// ---------------------------------------------------------------------------
// async global->LDS 16B copy (wave-uniform LDS base + lane*16, m104)
// ---------------------------------------------------------------------------
__device__ inline void async_lds16(const void* g, void* l) {
  __builtin_amdgcn_global_load_lds(
      (__attribute__((address_space(1))) void*)(g),
      (__attribute__((address_space(3))) void*)(l), 16, 0, 0);
}

#define MFMA16 __builtin_amdgcn_mfma_f32_16x16x32_bf16

// ---------------------------------------------------------------------------
// Fused attention (round-16 = round-14 EXACT + exp2 fold only).
// Block = (qb, h, b, vh): 64 Q-rows x 256 V-cols (4 rules), KVBLK=128.
// QK^T duplicated across the 2 vh-blocks; acc 32 AGPR; Q re-read from LDS
// per step (r15's Q-hoist spilled to scratch: WRITE 65->134 MB — reverted).
// Logits are base-2 (0.125*log2e folded into Wq/bq) so exp2f -> v_exp_f32.
// ---------------------------------------------------------------------------
__global__ __launch_bounds__(512, 4)
void attn_kernel(const bf16* __restrict__ qkv, const bf16* __restrict__ vT,
                 bf16* __restrict__ outb) {
  __shared__ __align__(16) bf16 Qs[64 * 64];        // 8 KB
  __shared__ __align__(16) bf16 Ks[2][128 * 64];    // 32 KB
  __shared__ __align__(16) bf16 Ps[2][64 * 128];    // 32 KB (step-parity dbuf)
  __shared__ float rsAll[8][64];
  __shared__ float rsInv[64];

  const int tid = threadIdx.x;
  const int lane = tid & 63, w = tid >> 6;
  const int r16 = lane & 15, rq = lane >> 4;

  // bijective XCD-chunked decode (nwg = 2048 = 8 * 256):
  // each XCD owns one (b, vh) slice -> K+V working set ~2 MB, L2-resident.
  const int flat = blockIdx.x + 32 * (blockIdx.y + 8 * blockIdx.z);
  const int swz = (flat & 7) * 256 + (flat >> 3);
  const int qb = swz & 31, h = (swz >> 5) & 7;
  const int zz = swz >> 8, b = zz >> 1, vh = zz & 1;

  // ---- stage Q tile [64 rows][64 d] (head h = q cols h*64..) ----
  const bf16* qbase = qkv + ((long)b * SEQ + qb * 64) * QKVW + h * 64;
  {
    const int rr = tid >> 3, sl = tid & 7;
    async_lds16(qbase + (long)rr * QKVW + ((sl ^ (rr & 7)) << 3),
                Qs + (size_t)w * 512);                 // wave-uniform base
  }
  // ---- K staging [128 rows][64 d], 2 chunks/thread ----
  const bf16* kbase = qkv + (long)b * SEQ * QKVW + 512 + h * 64;
  auto stageK = [&](int buf, int t0) {
#pragma unroll
    for (int g = 0; g < 2; g++) {
      const int c = g * 512 + tid;                   // lane-contiguous
      const int rr = c >> 3, sl = c & 7;
      async_lds16(kbase + (long)(t0 + rr) * QKVW + ((sl ^ (rr & 7)) << 3),
                  Ks[buf] + (size_t)(g * 8 + w) * 512);
    }
  };
  // per-lane V row pointers: this block's cols = vh*256 + w*32 + n*16 + r16
  const bf16* vp[2];
#pragma unroll
  for (int n = 0; n < 2; n++)
    vp[n] = vT + ((long)b * 512 + vh * 256 + w * 32 + n * 16 + r16) * SEQ + rq * 8;

  f32x4 acc[4][2] = {};   // [m-frag][n-frag] -> 32 AGPR
  float rs[4] = {};       // row-sum partials (per j)

  stageK(0, 0);
  asm volatile("s_waitcnt vmcnt(0)" ::: "memory");
  __builtin_amdgcn_s_barrier();
  __builtin_amdgcn_sched_barrier(0);

  const int krow = w * 16 + r16;              // this wave's key row (16 keys)
  for (int t = 0; t < 16; ++t) {
    const int t0 = t * 128;
    // ---- V groups 0,1 (this block's 2 col-frags each) issued FIRST ----
    bf16x8 v0[2], v1[2];
#pragma unroll
    for (int n = 0; n < 2; n++) v0[n] = *(const bf16x8*)(vp[n] + t0);
#pragma unroll
    for (int n = 0; n < 2; n++) v1[n] = *(const bf16x8*)(vp[n] + t0 + 32);
    __builtin_amdgcn_sched_barrier(0);
    if (t < 15) {
      stageK((t + 1) & 1, t0 + 128);        // K(t+1) prefetch
      __builtin_amdgcn_sched_barrier(0);
      asm volatile("s_waitcnt vmcnt(8)" ::: "memory");   // K(t) resident
    } else {
      asm volatile("s_waitcnt vmcnt(4)" ::: "memory");
    }
    __builtin_amdgcn_s_barrier();            // K(t) visible to all waves
    __builtin_amdgcn_sched_barrier(0);
    // ---- QK^T (swapped: S^T[key][qrow]); Q frags re-read from LDS ----
    f32x4 s4[4] = {};
#pragma unroll
    for (int kf = 0; kf < 2; kf++) {
      const bf16x8 kk = *(const bf16x8*)&Ks[t & 1][krow * 64 + (((kf * 4 + rq) ^ (krow & 7)) << 3)];
#pragma unroll
      for (int j = 0; j < 4; j++) {
        const int row = j * 16 + r16;
        const bf16x8 qq = *(const bf16x8*)&Qs[row * 64 + (((kf * 4 + rq) ^ (row & 7)) << 3)];
        s4[j] = MFMA16(kk, qq, s4[j], 0, 0, 0);
      }
    }
    // ---- exp2 + row-sum + pack P (keys w*16+rq*4+0..3, qrow j*16+r16) ----
    bf16* Pcur = Ps[t & 1];
#pragma unroll
    for (int j = 0; j < 4; j++) {
      const float e0 = exp2f(s4[j][0]), e1 = exp2f(s4[j][1]);
      const float e2 = exp2f(s4[j][2]), e3 = exp2f(s4[j][3]);
      rs[j] += (e0 + e1) + (e2 + e3);
      bf16x4 pk; pk[0] = (bf16)e0; pk[1] = (bf16)e1; pk[2] = (bf16)e2; pk[3] = (bf16)e3;
      const int row = j * 16 + r16;
      *(bf16x4*)&Pcur[row * 128 + (((w * 2 + (rq >> 1)) ^ (row & 7)) << 3) + ((rq & 1) << 2)] = pk;
    }
    asm volatile("s_waitcnt lgkmcnt(0)" ::: "memory");   // P writes drained
    __builtin_amdgcn_s_barrier();            // P(t) ready
    __builtin_amdgcn_sched_barrier(0);
    // ---- PV: acc += P[64 x 128] @ V[128 x 32(wave)], rolling V prefetch ----
#pragma unroll
    for (int g = 0; g < 4; g++) {
      bf16x8 v2[2];
      if (g < 2) {
#pragma unroll
        for (int n = 0; n < 2; n++)
          v2[n] = *(const bf16x8*)(vp[n] + t0 + (g + 2) * 32);
      }
      bf16x8 pf[4];
#pragma unroll
      for (int i = 0; i < 4; i++) {
        const int row = i * 16 + r16;
        pf[i] = *(const bf16x8*)&Ps[t & 1][row * 128 + (((rq + g * 4) ^ (row & 7)) << 3)];
      }
      __builtin_amdgcn_s_setprio(1);
#pragma unroll
      for (int i = 0; i < 4; i++) {
        acc[i][0] = MFMA16(pf[i], v0[0], acc[i][0], 0, 0, 0);
        acc[i][1] = MFMA16(pf[i], v0[1], acc[i][1], 0, 0, 0);
      }
      __builtin_amdgcn_s_setprio(0);
#pragma unroll
      for (int n = 0; n < 2; n++) { v0[n] = v1[n]; v1[n] = v2[n]; }  // renamed
    }
    // no end-of-step barrier: P step-dbuf'd (WAR is 2 barriers away)
  }

  // ---- epilogue: row-sum reduce (rq lanes -> waves) + normalize + store ----
#pragma unroll
  for (int j = 0; j < 4; j++) {
    rs[j] += __shfl_xor(rs[j], 16);
    rs[j] += __shfl_xor(rs[j], 32);
  }
  if (rq == 0) {
#pragma unroll
    for (int j = 0; j < 4; j++) rsAll[w][j * 16 + r16] = rs[j];
  }
  asm volatile("s_waitcnt lgkmcnt(0)" ::: "memory");
  __builtin_amdgcn_s_barrier();
  if (tid < 64) {
    float tot = 0.f;
#pragma unroll
    for (int u = 0; u < 8; u++) tot += rsAll[u][tid];
    rsInv[tid] = 1.f / tot;
  }
  asm volatile("s_waitcnt lgkmcnt(0)" ::: "memory");
  __builtin_amdgcn_s_barrier();

  bf16* obase = outb + (((long)(b * NH + h) * SEQ) + qb * 64) * 512 + vh * 256 + w * 32;
#pragma unroll
  for (int i = 0; i < 4; i++) {
#pragma unroll
    for (int rg = 0; rg < 4; rg++) {
      const int row = i * 16 + rq * 4 + rg;
      const float inv = rsInv[row];
#pragma unroll
      for (int n = 0; n < 2; n++)
        obase[(long)row * 512 + n * 16 + r16] = (bf16)(acc[i][n][rg] * inv);
    }
  }
}

// ---------------------------------------------------------------------------
// bf16 MFMA GEMM, 128x128 tile, BK=32, 4 waves, 3-deep counted-vmcnt pipeline
// (T3+T4) + T1 XCD-chunked block swizzle + T5 setprio.  [round-4 proven loop]
// bias applied only on the z==0 slice. flags: bit0 = bf16 out, bit1 = relu.
// Split-K: sAz/sBz = per-z K-offsets (elements), sCz = partial-buffer stride.
// ---------------------------------------------------------------------------
__global__ __launch_bounds__(256)
void gemm_bt(const bf16* __restrict__ A, const bf16* __restrict__ B,
             void* __restrict__ C, const float* __restrict__ bias,
             int K, int lda, int ldb, int ldc,
             long sAz, long sBz, long sCz,
             float scale, int flags) {
  constexpr int LPT = 4;
  __shared__ __align__(16) bf16 As[3][128 * 32];
  __shared__ __align__(16) bf16 Bs[3][128 * 32];

  const int tid  = threadIdx.x;
  const int lane = tid & 63;
  const int w    = tid >> 6;
  const int wr   = w >> 1, wc = w & 1;

  const int gx = gridDim.x, gy = gridDim.y;
  const int nwg = gx * gy * gridDim.z;
  const int flat = blockIdx.x + gx * (blockIdx.y + gy * blockIdx.z);
  const int q = nwg >> 3, r = nwg & 7;
  const int xcd = flat & 7, pos = flat >> 3;
  int swz = (xcd < r ? xcd * (q + 1) : r * (q + 1) + (xcd - r) * q) + pos;
  const int bx = swz % gx; swz /= gx;
  const int by = swz % gy;
  const long z = swz / gy;

  const bf16* Ab = A + (long)by * 128 * lda + z * sAz;
  const bf16* Bb = B + (long)bx * 128 * ldb + z * sBz;

  const bf16* aSrc[2];
  const bf16* bSrc[2];
#pragma unroll
  for (int g = 0; g < 2; g++) {
    const int c = (w * 2 + g) * 64 + lane;
    const int rr = c >> 2, sl = c & 3;
    aSrc[g] = Ab + (long)rr * lda + ((sl ^ ((rr >> 1) & 3)) << 3);
    bSrc[g] = Bb + (long)rr * ldb + ((sl ^ ((rr >> 1) & 3)) << 3);
  }

  f32x4 acc[4][4] = {};
  const int r16 = lane & 15, kq = lane >> 4;
  const int so = ((kq ^ ((r16 >> 1) & 3)) << 3);

  auto stage = [&](int buf, int k0) {
#pragma unroll
    for (int g = 0; g < 2; g++)
      async_lds16(aSrc[g] + k0, &As[buf][(w * 2 + g) * 512]);
#pragma unroll
    for (int g = 0; g < 2; g++)
      async_lds16(bSrc[g] + k0, &Bs[buf][(w * 2 + g) * 512]);
  };
  bf16x8 areg[4], breg[4];
  auto loadfrags = [&](int buf) {
#pragma unroll
    for (int i = 0; i < 4; i++)
      areg[i] = *(const bf16x8*)&As[buf][(wr * 64 + i * 16 + r16) * 32 + so];
#pragma unroll
    for (int j = 0; j < 4; j++)
      breg[j] = *(const bf16x8*)&Bs[buf][(wc * 64 + j * 16 + r16) * 32 + so];
  };
  auto domfma = [&]() {
    __builtin_amdgcn_s_setprio(1);
#pragma unroll
    for (int i = 0; i < 4; i++)
#pragma unroll
      for (int j = 0; j < 4; j++)
        acc[i][j] = MFMA16(areg[i], breg[j], acc[i][j], 0, 0, 0);
    __builtin_amdgcn_s_setprio(0);
  };

  const int nt = K >> 5;
  stage(0, 0);
  if (nt > 1) stage(1, 32);

  int cs = 2, cc = 0;
  for (int t = 0; t + 2 < nt; ++t) {
    stage(cs, (t + 2) * 32);
    asm volatile("s_waitcnt vmcnt(%0)" : : "n"(2 * LPT) : "memory");
    __builtin_amdgcn_s_barrier();
    loadfrags(cc);
    asm volatile("s_waitcnt lgkmcnt(0)" : : : "memory");
    __builtin_amdgcn_sched_barrier(0);
    __builtin_amdgcn_s_barrier();
    domfma();
    if (++cs == 3) cs = 0;
    if (++cc == 3) cc = 0;
  }
  if (nt >= 2) {
    asm volatile("s_waitcnt vmcnt(%0)" : : "n"(LPT) : "memory");
    __builtin_amdgcn_s_barrier();
    loadfrags(cc);
    asm volatile("s_waitcnt lgkmcnt(0)" : : : "memory");
    __builtin_amdgcn_sched_barrier(0);
    domfma();
    if (++cc == 3) cc = 0;
  }
  asm volatile("s_waitcnt vmcnt(0)" : : : "memory");
  __builtin_amdgcn_s_barrier();
  loadfrags(cc);
  domfma();

  const long rowBase = (long)by * 128 + wr * 64;
  const int  colBase = bx * 128 + wc * 64;
  float* Cf = (float*)C;
  bf16*  Cb = (bf16*)C;
  const int rq = lane >> 4;
#pragma unroll
  for (int i = 0; i < 4; i++) {
#pragma unroll
    for (int j = 0; j < 4; j++) {
      const int col = colBase + j * 16 + r16;
      const float bv = (bias && z == 0) ? bias[col] : 0.f;
#pragma unroll
      for (int rg = 0; rg < 4; rg++) {
        const long row = rowBase + i * 16 + rq * 4 + rg;
        float y = (acc[i][j][rg] + bv) * scale;
        if (flags & 2) y = fmaxf(y, 0.f);
        const long idx = z * sCz + row * (long)ldc + col;
        if (flags & 1) Cb[idx] = (bf16)y;
        else           Cf[idx] = y;
      }
    }
  }
}

// ---------------------------------------------------------------------------
__global__ void transpose_w_kernel(const float* __restrict__ in, bf16* __restrict__ out,
                                   int K, int N, float scale) {
  __shared__ float t[32][33];
  const int n0 = blockIdx.x * 32, k0 = blockIdx.y * 32;
  const int tx = threadIdx.x, ty = threadIdx.y;
#pragma unroll
  for (int i = ty; i < 32; i += 8)
    t[i][tx] = in[(long)(k0 + i) * N + n0 + tx];
  __syncthreads();
#pragma unroll
  for (int i = ty; i < 32; i += 8)
    out[(long)(n0 + i) * K + k0 + tx] = (bf16)(t[tx][i] * scale);
}

__global__ void build_bias_kernel(const float* bq, const float* bk,
                                  const float* bv, const float* bqv,
                                  float* __restrict__ out) {
  const int i = blockIdx.x * 256 + threadIdx.x;
  float v;
  if (i < 512)       v = bq[i] * 0.18033688011112042f;   // 0.125 * log2(e)
  else if (i < 1024) v = bk[i - 512];
  else if (i < 1536) v = bv[i - 1024];
  else               v = bqv[i - 1536] * 0.17677669529663687f;
  out[i] = v;
}

// v (cols 1024..1535 of qkv) -> vT bf16 [B][512][S]
__global__ void transpose_v_kernel(const bf16* __restrict__ qkv, bf16* __restrict__ vT) {
  __shared__ bf16 t[32][33];
  const int s0 = blockIdx.x * 32, c0 = blockIdx.y * 32, b = blockIdx.z;
  const int tx = threadIdx.x, ty = threadIdx.y;
#pragma unroll
  for (int i = ty; i < 32; i += 8)
    t[i][tx] = qkv[((long)b * SEQ + s0 + i) * QKVW + 1024 + c0 + tx];
  __syncthreads();
#pragma unroll
  for (int i = ty; i < 32; i += 8)
    vT[(long)b * 512 * SEQ + (long)(c0 + i) * SEQ + s0 + tx] = t[tx][i];
}

// x f32 [S][B][D] -> xb bf16 [B*S][D]
__global__ __launch_bounds__(256)
void convert_x_kernel(const float* __restrict__ x, bf16* __restrict__ xb) {
  const long i0 = ((long)blockIdx.x * 256 + threadIdx.x) * 8;
  const int t = (int)(i0 >> 9), d = (int)(i0 & 511);
  const int b = t >> 11, s = t & 2047;
  const float* src = x + ((long)(s * BAT + b) << 9) + d;
  const float4 f0 = *(const float4*)(src);
  const float4 f1 = *(const float4*)(src + 4);
  bf16x8 o;
  o[0] = (bf16)f0.x; o[1] = (bf16)f0.y; o[2] = (bf16)f0.z; o[3] = (bf16)f0.w;
  o[4] = (bf16)f1.x; o[5] = (bf16)f1.y; o[6] = (bf16)f1.z; o[7] = (bf16)f1.w;
  *(bf16x8*)&xb[i0] = o;
}

// ---------------------------------------------------------------------------
// Stage-2 composition: one wave per (b,h,s).
// ---------------------------------------------------------------------------
__global__ __launch_bounds__(256)
void stage2_kernel(const bf16* __restrict__ outbuf, long strideB,
                   const bf16* __restrict__ qvb, int qvStride,
                   const float* __restrict__ Wkv,
                   const float* __restrict__ bkv,
                   bf16* __restrict__ attn) {
  const int lane = threadIdx.x & 63, wid = threadIdx.x >> 6;
  const int g = blockIdx.x * 4 + wid;
  const int s = g & 2047, h = (g >> 11) & 7, b = g >> 14;
  const int token = b * SEQ + s;

  const bf16* qv = qvb + (long)token * qvStride + h * 32;
  const float* wrow = Wkv + lane * 32;
  float wq = 0.f, cb = 0.f;
#pragma unroll 8
  for (int q = 0; q < 32; q++) {
    const float qf = (float)qv[q];
    wq += wrow[q] * qf;
    cb += bkv[q] * qf;
  }

  const bf16* orow = outbuf + b * strideB + ((long)(h << 11) + s) * 512;
  float of[8], lg[8];
#pragma unroll
  for (int r = 0; r < 8; r++) {
    of[r] = (float)orow[r * 64 + lane];
    float p = of[r] * wq;
    for (int o = 1; o < 64; o <<= 1) p += __shfl_xor(p, o);
    lg[r] = p + cb;
  }
  float m = lg[0];
#pragma unroll
  for (int r = 1; r < 8; r++) m = fmaxf(m, lg[r]);
  float e[8], sum = 0.f;
#pragma unroll
  for (int r = 0; r < 8; r++) { e[r] = __expf(lg[r] - m); sum += e[r]; }
  const float inv = 1.f / sum;
  float o = 0.f;
#pragma unroll
  for (int r = 0; r < 8; r++) o += e[r] * inv * of[r];
  attn[(long)token * 512 + h * 64 + lane] = (bf16)o;
}

// ---------------------------------------------------------------------------
// LayerNorm over D=512 per token; optional split-K partial at +part2 elems.
// ---------------------------------------------------------------------------
__global__ __launch_bounds__(256)
void ln_kernel(const float* __restrict__ a, long part2,
               const float* __restrict__ bres, int bresT,
               const float* __restrict__ g, const float* __restrict__ be,
               float* __restrict__ outF, bf16* __restrict__ outB, int outT) {
  __shared__ float red[8];
  const int t = blockIdx.x, tid = threadIdx.x;
  const int b = t >> 11, s = t & 2047;
  const long ti = (long)t * 512;
  const long xi = (long)(s * BAT + b) * 512;
  const long ri = bresT ? xi : ti;
  float v0 = a[ti + tid]       + bres[ri + tid];
  float v1 = a[ti + 256 + tid] + bres[ri + 256 + tid];
  if (part2) { v0 += a[part2 + ti + tid]; v1 += a[part2 + ti + 256 + tid]; }
  float sum = v0 + v1, sq = v0 * v0 + v1 * v1;
  const int lane = tid & 63, wid = tid >> 6;
  for (int o = 1; o < 64; o <<= 1) { sum += __shfl_xor(sum, o); sq += __shfl_xor(sq, o); }
  if (lane == 0) { red[wid] = sum; red[4 + wid] = sq; }
  __syncthreads();
  sum = red[0] + red[1] + red[2] + red[3];
  sq  = red[4] + red[5] + red[6] + red[7];
  const float mu = sum * (1.f / 512.f);
  const float var = sq * (1.f / 512.f) - mu * mu;
  const float rs = rsqrtf(var + 1e-5f);
  const float y0 = (v0 - mu) * rs * g[tid] + be[tid];
  const float y1 = (v1 - mu) * rs * g[tid + 256] + be[tid + 256];
  const long oi = outT ? xi : ti;
  if (outF) { outF[oi + tid] = y0; outF[oi + 256 + tid] = y1; }
  if (outB) { outB[ti + tid] = (bf16)y0; outB[ti + 256 + tid] = (bf16)y1; }
}

// ---------------------------------------------------------------------------
extern "C" void kernel_launch(void* const* d_in, const int* in_sizes, int n_in,
                              void* d_out, int out_size, void* d_ws, size_t ws_size,
                              hipStream_t stream) {
  const float* x   = (const float*)d_in[0];
  const float* Wq  = (const float*)d_in[1];
  const float* bq  = (const float*)d_in[2];
  const float* Wk  = (const float*)d_in[3];
  const float* bk  = (const float*)d_in[4];
  const float* Wv  = (const float*)d_in[5];
  const float* bv  = (const float*)d_in[6];
  const float* Wqv = (const float*)d_in[7];
  const float* bqv = (const float*)d_in[8];
  const float* Wkv = (const float*)d_in[9];
  const float* bkv = (const float*)d_in[10];
  const float* Wf  = (const float*)d_in[11];
  const float* bfc = (const float*)d_in[12];
  const float* W1  = (const float*)d_in[13];
  const float* b1  = (const float*)d_in[14];
  const float* W2  = (const float*)d_in[15];
  const float* b2  = (const float*)d_in[16];
  const float* g1  = (const float*)d_in[17];
  const float* be1 = (const float*)d_in[18];
  const float* g2  = (const float*)d_in[19];
  const float* be2 = (const float*)d_in[20];

  char* ws = (char*)d_ws;
  size_t off = 0;
  auto alloc = [&](size_t bytes) -> void* {
    void* p = ws + off;
    off += (bytes + 1023) & ~(size_t)1023;
    return p;
  };
  // ---- persistent (~50 MB) ----
  bf16*  qkv   = (bf16*)alloc((size_t)NTOK * QKVW * 2);
  bf16*  vT    = (bf16*)alloc((size_t)BAT * 512 * SEQ * 2);
  bf16*  wtPk  = (bf16*)alloc((size_t)QKVW * 512 * 2);
  bf16*  WfT   = (bf16*)alloc(512 * 512 * 2);
  bf16*  W1T   = (bf16*)alloc((size_t)2048 * 512 * 2);
  bf16*  W2T   = (bf16*)alloc((size_t)512 * 2048 * 2);
  float* bcat  = (float*)alloc(QKVW * 4);
  bf16*  attn  = (bf16*)alloc((size_t)NTOK * 512 * 2);

  // ---- shared region (96 MB), phases temporally disjoint ----
  // attn phase: [outb 64]    ffn phase: [xb 8 | wfoP 32 | ln1f 16 | ln1b 8 | ffn1 32]
  char* reg = ws + off;
  bf16*  outb  = (bf16*)reg;                 //  0..64 (dead after stage2)
  bf16*  xb    = (bf16*)reg;                 //  0..8  (dead after projection)
  float* wfoP  = (float*)(reg + 8 * MB);     //  8..40 (2 f32 partials)
  float* ln1f  = (float*)(reg + 40 * MB);    // 40..56
  bf16*  ln1b  = (bf16*)(reg + 56 * MB);     // 56..64
  bf16*  ffn1  = (bf16*)(reg + 64 * MB);     // 64..96

  const dim3 tb(32, 8);
  // q scale folds softmax's 1/sqrt(64) AND log2(e) so attn can use exp2
  transpose_w_kernel<<<dim3(16, 16), tb, 0, stream>>>(Wq,  wtPk,              512, 512, 0.18033688011112042f);
  transpose_w_kernel<<<dim3(16, 16), tb, 0, stream>>>(Wk,  wtPk + 512  * 512, 512, 512, 1.f);
  transpose_w_kernel<<<dim3(16, 16), tb, 0, stream>>>(Wv,  wtPk + 1024 * 512, 512, 512, 1.f);
  transpose_w_kernel<<<dim3(8, 16),  tb, 0, stream>>>(Wqv, wtPk + 1536 * 512, 512, 256, 0.17677669529663687f);
  transpose_w_kernel<<<dim3(16, 16), tb, 0, stream>>>(Wf,  WfT, 512, 512, 1.f);
  transpose_w_kernel<<<dim3(64, 16), tb, 0, stream>>>(W1,  W1T, 512, 2048, 1.f);
  transpose_w_kernel<<<dim3(16, 64), tb, 0, stream>>>(W2,  W2T, 2048, 512, 1.f);
  build_bias_kernel<<<7, 256, 0, stream>>>(bq, bk, bv, bqv, bcat);
  convert_x_kernel<<<2048, 256, 0, stream>>>(x, xb);

  // fused q|k|v|qv projection: [8192,512] @ [1792,512]^T -> [8192,1792]
  gemm_bt<<<dim3(14, 64, 1), 256, 0, stream>>>(xb, wtPk, qkv, bcat,
      512, 512, 512, QKVW, 0, 0, 0, 1.f, 1);

  transpose_v_kernel<<<dim3(64, 16, 4), tb, 0, stream>>>(qkv, vT);

  // fused attention: score+softmax+PV; V-cols split across z (2 blocks/CU)
  attn_kernel<<<dim3(SEQ / 64, NH, BAT * 2), 512, 0, stream>>>(qkv, vT, outb);

  stage2_kernel<<<BAT * NH * SEQ / 4, 256, 0, stream>>>(outb, (long)NH * SEQ * 512,
      qkv + 1536, QKVW, Wkv, bkv, attn);

  const long sWf = (long)NTOK * 512;
  // Wf projection, split-K z=2, f32 partials (bias on z==0), summed by ln1
  gemm_bt<<<dim3(4, 64, 2), 256, 0, stream>>>(attn, WfT, wfoP, bfc,
      256, 512, 512, 512, 256, 256, sWf, 1.f, 0);
  ln_kernel<<<NTOK, 256, 0, stream>>>(wfoP, sWf, x, 1, g1, be1, ln1f, ln1b, 0);
  gemm_bt<<<dim3(16, 64, 1), 256, 0, stream>>>(ln1b, W1T, ffn1, b1,
      512, 512, 512, 2048, 0, 0, 0, 1.f, 1 | 2);
  // ffn2, split-K z=2, f32 partials (bias on z==0), summed by ln2
  gemm_bt<<<dim3(4, 64, 2), 256, 0, stream>>>(ffn1, W2T, wfoP, b2,
      1024, 2048, 2048, 512, 1024, 1024, sWf, 1.f, 0);
  ln_kernel<<<NTOK, 256, 0, stream>>>(wfoP, sWf, ln1f, 0, g2, be2, (float*)d_out, nullptr, 1);
}

// Round 17
// 513.838 us; speedup vs baseline: 1.1227x; 1.0055x over previous
//
#include <hip/hip_runtime.h>
#include <hip/hip_bf16.h>

typedef __bf16 bf16;
typedef bf16 bf16x4 __attribute__((ext_vector_type(4)));
typedef bf16 bf16x8 __attribute__((ext_vector_type(8)));
typedef float f32x4 __attribute__((ext_vector_type(4)));

constexpr int SEQ  = 2048;
constexpr int BAT  = 4;
constexpr int NH   = 8;
constexpr int NTOK = SEQ * BAT;   // 8192
constexpr int QKVW = 1792;        // fused projection width: 512+512+512+256
constexpr size_t MB = 1ull << 20;

// ---------------------------------------------------------------------------
// async global->LDS 16B copy (wave-uniform LDS base + lane*16, m104)
// ---------------------------------------------------------------------------
__device__ inline void async_lds16(const void* g, void* l) {
  __builtin_amdgcn_global_load_lds(
      (__attribute__((address_space(1))) void*)(g),
      (__attribute__((address_space(3))) void*)(l), 16, 0, 0);
}

#define MFMA16 __builtin_amdgcn_mfma_f32_16x16x32_bf16

// ---------------------------------------------------------------------------
// Fused attention (round-17 = round-16 + KV-loop unrolled x2).
// Block = (qb, h, b, vh): 64 Q-rows x 256 V-cols (4 rules), KVBLK=128.
// Unroll makes buffer parity compile-time: Ps[0/1], Ks[0/1] are static LDS
// bases -> the +16KB buffer select folds into ds_read/ds_write immediate
// offsets instead of a v_add per access (measured VALUBusy ~31% dominated
// by LDS addressing at the compiler's 64-VGPR budget).
// ---------------------------------------------------------------------------
__global__ __launch_bounds__(512, 4)
void attn_kernel(const bf16* __restrict__ qkv, const bf16* __restrict__ vT,
                 bf16* __restrict__ outb) {
  __shared__ __align__(16) bf16 Qs[64 * 64];        // 8 KB
  __shared__ __align__(16) bf16 Ks[2][128 * 64];    // 32 KB
  __shared__ __align__(16) bf16 Ps[2][64 * 128];    // 32 KB (step-parity dbuf)
  __shared__ float rsAll[8][64];
  __shared__ float rsInv[64];

  const int tid = threadIdx.x;
  const int lane = tid & 63, w = tid >> 6;
  const int r16 = lane & 15, rq = lane >> 4;

  // bijective XCD-chunked decode (nwg = 2048 = 8 * 256):
  // each XCD owns one (b, vh) slice -> K+V working set ~2 MB, L2-resident.
  const int flat = blockIdx.x + 32 * (blockIdx.y + 8 * blockIdx.z);
  const int swz = (flat & 7) * 256 + (flat >> 3);
  const int qb = swz & 31, h = (swz >> 5) & 7;
  const int zz = swz >> 8, b = zz >> 1, vh = zz & 1;

  // ---- stage Q tile [64 rows][64 d] (head h = q cols h*64..) ----
  const bf16* qbase = qkv + ((long)b * SEQ + qb * 64) * QKVW + h * 64;
  {
    const int rr = tid >> 3, sl = tid & 7;
    async_lds16(qbase + (long)rr * QKVW + ((sl ^ (rr & 7)) << 3),
                Qs + (size_t)w * 512);                 // wave-uniform base
  }
  // ---- K staging [128 rows][64 d], 2 chunks/thread ----
  const bf16* kbase = qkv + (long)b * SEQ * QKVW + 512 + h * 64;
  auto stageK = [&](bf16* dst, int t0) {
#pragma unroll
    for (int g = 0; g < 2; g++) {
      const int c = g * 512 + tid;                   // lane-contiguous
      const int rr = c >> 3, sl = c & 7;
      async_lds16(kbase + (long)(t0 + rr) * QKVW + ((sl ^ (rr & 7)) << 3),
                  dst + (size_t)(g * 8 + w) * 512);
    }
  };
  // per-lane V row pointers: this block's cols = vh*256 + w*32 + n*16 + r16
  const bf16* vp[2];
#pragma unroll
  for (int n = 0; n < 2; n++)
    vp[n] = vT + ((long)b * 512 + vh * 256 + w * 32 + n * 16 + r16) * SEQ + rq * 8;

  f32x4 acc[4][2] = {};   // [m-frag][n-frag] -> 32 AGPR
  float rs[4] = {};       // row-sum partials (per j)

  stageK(Ks[0], 0);
  asm volatile("s_waitcnt vmcnt(0)" ::: "memory");
  __builtin_amdgcn_s_barrier();
  __builtin_amdgcn_sched_barrier(0);

  const int krow = w * 16 + r16;              // this wave's key row (16 keys)

  // one KV step; Pcur/Kread/Kwrite are statically-known LDS bases (unrolled)
  auto stepf = [&](int t0, bf16* __restrict__ Pcur,
                   const bf16* __restrict__ Kread,
                   bf16* __restrict__ Kwrite, bool doStage) {
    // ---- V groups 0,1 issued FIRST ----
    bf16x8 v0[2], v1[2];
#pragma unroll
    for (int n = 0; n < 2; n++) v0[n] = *(const bf16x8*)(vp[n] + t0);
#pragma unroll
    for (int n = 0; n < 2; n++) v1[n] = *(const bf16x8*)(vp[n] + t0 + 32);
    __builtin_amdgcn_sched_barrier(0);
    if (doStage) {
      stageK(Kwrite, t0 + 128);             // K(t+1) prefetch
      __builtin_amdgcn_sched_barrier(0);
      asm volatile("s_waitcnt vmcnt(8)" ::: "memory");   // K(t) resident
    } else {
      asm volatile("s_waitcnt vmcnt(4)" ::: "memory");
    }
    __builtin_amdgcn_s_barrier();            // K(t) visible to all waves
    __builtin_amdgcn_sched_barrier(0);
    // ---- QK^T (swapped: S^T[key][qrow]); Q frags re-read from LDS ----
    f32x4 s4[4] = {};
#pragma unroll
    for (int kf = 0; kf < 2; kf++) {
      const bf16x8 kk = *(const bf16x8*)&Kread[krow * 64 + (((kf * 4 + rq) ^ (krow & 7)) << 3)];
#pragma unroll
      for (int j = 0; j < 4; j++) {
        const int row = j * 16 + r16;
        const bf16x8 qq = *(const bf16x8*)&Qs[row * 64 + (((kf * 4 + rq) ^ (row & 7)) << 3)];
        s4[j] = MFMA16(kk, qq, s4[j], 0, 0, 0);
      }
    }
    // ---- exp2 + row-sum + pack P (keys w*16+rq*4+0..3, qrow j*16+r16) ----
#pragma unroll
    for (int j = 0; j < 4; j++) {
      const float e0 = exp2f(s4[j][0]), e1 = exp2f(s4[j][1]);
      const float e2 = exp2f(s4[j][2]), e3 = exp2f(s4[j][3]);
      rs[j] += (e0 + e1) + (e2 + e3);
      bf16x4 pk; pk[0] = (bf16)e0; pk[1] = (bf16)e1; pk[2] = (bf16)e2; pk[3] = (bf16)e3;
      const int row = j * 16 + r16;
      *(bf16x4*)&Pcur[row * 128 + (((w * 2 + (rq >> 1)) ^ (row & 7)) << 3) + ((rq & 1) << 2)] = pk;
    }
    asm volatile("s_waitcnt lgkmcnt(0)" ::: "memory");   // P writes drained
    __builtin_amdgcn_s_barrier();            // P(t) ready
    __builtin_amdgcn_sched_barrier(0);
    // ---- PV: acc += P[64 x 128] @ V[128 x 32(wave)], rolling V prefetch ----
#pragma unroll
    for (int g = 0; g < 4; g++) {
      bf16x8 v2[2];
      if (g < 2) {
#pragma unroll
        for (int n = 0; n < 2; n++)
          v2[n] = *(const bf16x8*)(vp[n] + t0 + (g + 2) * 32);
      }
      bf16x8 pf[4];
#pragma unroll
      for (int i = 0; i < 4; i++) {
        const int row = i * 16 + r16;
        pf[i] = *(const bf16x8*)&Pcur[row * 128 + (((rq + g * 4) ^ (row & 7)) << 3)];
      }
      __builtin_amdgcn_s_setprio(1);
#pragma unroll
      for (int i = 0; i < 4; i++) {
        acc[i][0] = MFMA16(pf[i], v0[0], acc[i][0], 0, 0, 0);
        acc[i][1] = MFMA16(pf[i], v0[1], acc[i][1], 0, 0, 0);
      }
      __builtin_amdgcn_s_setprio(0);
#pragma unroll
      for (int n = 0; n < 2; n++) { v0[n] = v1[n]; v1[n] = v2[n]; }  // renamed
    }
    // no end-of-step barrier: P step-dbuf'd (WAR is 2 barriers away)
  };

  for (int k8 = 0; k8 < 8; ++k8) {
    stepf(k8 * 256,       Ps[0], Ks[0], Ks[1], true);     // even step t=2k
    stepf(k8 * 256 + 128, Ps[1], Ks[1], Ks[0], k8 < 7);   // odd  step t=2k+1
  }

  // ---- epilogue: row-sum reduce (rq lanes -> waves) + normalize + store ----
#pragma unroll
  for (int j = 0; j < 4; j++) {
    rs[j] += __shfl_xor(rs[j], 16);
    rs[j] += __shfl_xor(rs[j], 32);
  }
  if (rq == 0) {
#pragma unroll
    for (int j = 0; j < 4; j++) rsAll[w][j * 16 + r16] = rs[j];
  }
  asm volatile("s_waitcnt lgkmcnt(0)" ::: "memory");
  __builtin_amdgcn_s_barrier();
  if (tid < 64) {
    float tot = 0.f;
#pragma unroll
    for (int u = 0; u < 8; u++) tot += rsAll[u][tid];
    rsInv[tid] = 1.f / tot;
  }
  asm volatile("s_waitcnt lgkmcnt(0)" ::: "memory");
  __builtin_amdgcn_s_barrier();

  bf16* obase = outb + (((long)(b * NH + h) * SEQ) + qb * 64) * 512 + vh * 256 + w * 32;
#pragma unroll
  for (int i = 0; i < 4; i++) {
#pragma unroll
    for (int rg = 0; rg < 4; rg++) {
      const int row = i * 16 + rq * 4 + rg;
      const float inv = rsInv[row];
#pragma unroll
      for (int n = 0; n < 2; n++)
        obase[(long)row * 512 + n * 16 + r16] = (bf16)(acc[i][n][rg] * inv);
    }
  }
}

// ---------------------------------------------------------------------------
// bf16 MFMA GEMM, 128x128 tile, BK=32, 4 waves, 3-deep counted-vmcnt pipeline
// (T3+T4) + T1 XCD-chunked block swizzle + T5 setprio.  [round-4 proven loop]
// bias applied only on the z==0 slice. flags: bit0 = bf16 out, bit1 = relu.
// Split-K: sAz/sBz = per-z K-offsets (elements), sCz = partial-buffer stride.
// ---------------------------------------------------------------------------
__global__ __launch_bounds__(256)
void gemm_bt(const bf16* __restrict__ A, const bf16* __restrict__ B,
             void* __restrict__ C, const float* __restrict__ bias,
             int K, int lda, int ldb, int ldc,
             long sAz, long sBz, long sCz,
             float scale, int flags) {
  constexpr int LPT = 4;
  __shared__ __align__(16) bf16 As[3][128 * 32];
  __shared__ __align__(16) bf16 Bs[3][128 * 32];

  const int tid  = threadIdx.x;
  const int lane = tid & 63;
  const int w    = tid >> 6;
  const int wr   = w >> 1, wc = w & 1;

  const int gx = gridDim.x, gy = gridDim.y;
  const int nwg = gx * gy * gridDim.z;
  const int flat = blockIdx.x + gx * (blockIdx.y + gy * blockIdx.z);
  const int q = nwg >> 3, r = nwg & 7;
  const int xcd = flat & 7, pos = flat >> 3;
  int swz = (xcd < r ? xcd * (q + 1) : r * (q + 1) + (xcd - r) * q) + pos;
  const int bx = swz % gx; swz /= gx;
  const int by = swz % gy;
  const long z = swz / gy;

  const bf16* Ab = A + (long)by * 128 * lda + z * sAz;
  const bf16* Bb = B + (long)bx * 128 * ldb + z * sBz;

  const bf16* aSrc[2];
  const bf16* bSrc[2];
#pragma unroll
  for (int g = 0; g < 2; g++) {
    const int c = (w * 2 + g) * 64 + lane;
    const int rr = c >> 2, sl = c & 3;
    aSrc[g] = Ab + (long)rr * lda + ((sl ^ ((rr >> 1) & 3)) << 3);
    bSrc[g] = Bb + (long)rr * ldb + ((sl ^ ((rr >> 1) & 3)) << 3);
  }

  f32x4 acc[4][4] = {};
  const int r16 = lane & 15, kq = lane >> 4;
  const int so = ((kq ^ ((r16 >> 1) & 3)) << 3);

  auto stage = [&](int buf, int k0) {
#pragma unroll
    for (int g = 0; g < 2; g++)
      async_lds16(aSrc[g] + k0, &As[buf][(w * 2 + g) * 512]);
#pragma unroll
    for (int g = 0; g < 2; g++)
      async_lds16(bSrc[g] + k0, &Bs[buf][(w * 2 + g) * 512]);
  };
  bf16x8 areg[4], breg[4];
  auto loadfrags = [&](int buf) {
#pragma unroll
    for (int i = 0; i < 4; i++)
      areg[i] = *(const bf16x8*)&As[buf][(wr * 64 + i * 16 + r16) * 32 + so];
#pragma unroll
    for (int j = 0; j < 4; j++)
      breg[j] = *(const bf16x8*)&Bs[buf][(wc * 64 + j * 16 + r16) * 32 + so];
  };
  auto domfma = [&]() {
    __builtin_amdgcn_s_setprio(1);
#pragma unroll
    for (int i = 0; i < 4; i++)
#pragma unroll
      for (int j = 0; j < 4; j++)
        acc[i][j] = MFMA16(areg[i], breg[j], acc[i][j], 0, 0, 0);
    __builtin_amdgcn_s_setprio(0);
  };

  const int nt = K >> 5;
  stage(0, 0);
  if (nt > 1) stage(1, 32);

  int cs = 2, cc = 0;
  for (int t = 0; t + 2 < nt; ++t) {
    stage(cs, (t + 2) * 32);
    asm volatile("s_waitcnt vmcnt(%0)" : : "n"(2 * LPT) : "memory");
    __builtin_amdgcn_s_barrier();
    loadfrags(cc);
    asm volatile("s_waitcnt lgkmcnt(0)" : : : "memory");
    __builtin_amdgcn_sched_barrier(0);
    __builtin_amdgcn_s_barrier();
    domfma();
    if (++cs == 3) cs = 0;
    if (++cc == 3) cc = 0;
  }
  if (nt >= 2) {
    asm volatile("s_waitcnt vmcnt(%0)" : : "n"(LPT) : "memory");
    __builtin_amdgcn_s_barrier();
    loadfrags(cc);
    asm volatile("s_waitcnt lgkmcnt(0)" : : : "memory");
    __builtin_amdgcn_sched_barrier(0);
    domfma();
    if (++cc == 3) cc = 0;
  }
  asm volatile("s_waitcnt vmcnt(0)" : : : "memory");
  __builtin_amdgcn_s_barrier();
  loadfrags(cc);
  domfma();

  const long rowBase = (long)by * 128 + wr * 64;
  const int  colBase = bx * 128 + wc * 64;
  float* Cf = (float*)C;
  bf16*  Cb = (bf16*)C;
  const int rq = lane >> 4;
#pragma unroll
  for (int i = 0; i < 4; i++) {
#pragma unroll
    for (int j = 0; j < 4; j++) {
      const int col = colBase + j * 16 + r16;
      const float bv = (bias && z == 0) ? bias[col] : 0.f;
#pragma unroll
      for (int rg = 0; rg < 4; rg++) {
        const long row = rowBase + i * 16 + rq * 4 + rg;
        float y = (acc[i][j][rg] + bv) * scale;
        if (flags & 2) y = fmaxf(y, 0.f);
        const long idx = z * sCz + row * (long)ldc + col;
        if (flags & 1) Cb[idx] = (bf16)y;
        else           Cf[idx] = y;
      }
    }
  }
}

// ---------------------------------------------------------------------------
__global__ void transpose_w_kernel(const float* __restrict__ in, bf16* __restrict__ out,
                                   int K, int N, float scale) {
  __shared__ float t[32][33];
  const int n0 = blockIdx.x * 32, k0 = blockIdx.y * 32;
  const int tx = threadIdx.x, ty = threadIdx.y;
#pragma unroll
  for (int i = ty; i < 32; i += 8)
    t[i][tx] = in[(long)(k0 + i) * N + n0 + tx];
  __syncthreads();
#pragma unroll
  for (int i = ty; i < 32; i += 8)
    out[(long)(n0 + i) * K + k0 + tx] = (bf16)(t[tx][i] * scale);
}

__global__ void build_bias_kernel(const float* bq, const float* bk,
                                  const float* bv, const float* bqv,
                                  float* __restrict__ out) {
  const int i = blockIdx.x * 256 + threadIdx.x;
  float v;
  if (i < 512)       v = bq[i] * 0.18033688011112042f;   // 0.125 * log2(e)
  else if (i < 1024) v = bk[i - 512];
  else if (i < 1536) v = bv[i - 1024];
  else               v = bqv[i - 1536] * 0.17677669529663687f;
  out[i] = v;
}

// v (cols 1024..1535 of qkv) -> vT bf16 [B][512][S]
__global__ void transpose_v_kernel(const bf16* __restrict__ qkv, bf16* __restrict__ vT) {
  __shared__ bf16 t[32][33];
  const int s0 = blockIdx.x * 32, c0 = blockIdx.y * 32, b = blockIdx.z;
  const int tx = threadIdx.x, ty = threadIdx.y;
#pragma unroll
  for (int i = ty; i < 32; i += 8)
    t[i][tx] = qkv[((long)b * SEQ + s0 + i) * QKVW + 1024 + c0 + tx];
  __syncthreads();
#pragma unroll
  for (int i = ty; i < 32; i += 8)
    vT[(long)b * 512 * SEQ + (long)(c0 + i) * SEQ + s0 + tx] = t[tx][i];
}

// x f32 [S][B][D] -> xb bf16 [B*S][D]
__global__ __launch_bounds__(256)
void convert_x_kernel(const float* __restrict__ x, bf16* __restrict__ xb) {
  const long i0 = ((long)blockIdx.x * 256 + threadIdx.x) * 8;
  const int t = (int)(i0 >> 9), d = (int)(i0 & 511);
  const int b = t >> 11, s = t & 2047;
  const float* src = x + ((long)(s * BAT + b) << 9) + d;
  const float4 f0 = *(const float4*)(src);
  const float4 f1 = *(const float4*)(src + 4);
  bf16x8 o;
  o[0] = (bf16)f0.x; o[1] = (bf16)f0.y; o[2] = (bf16)f0.z; o[3] = (bf16)f0.w;
  o[4] = (bf16)f1.x; o[5] = (bf16)f1.y; o[6] = (bf16)f1.z; o[7] = (bf16)f1.w;
  *(bf16x8*)&xb[i0] = o;
}

// ---------------------------------------------------------------------------
// Stage-2 composition: one wave per (b,h,s).
// ---------------------------------------------------------------------------
__global__ __launch_bounds__(256)
void stage2_kernel(const bf16* __restrict__ outbuf, long strideB,
                   const bf16* __restrict__ qvb, int qvStride,
                   const float* __restrict__ Wkv,
                   const float* __restrict__ bkv,
                   bf16* __restrict__ attn) {
  const int lane = threadIdx.x & 63, wid = threadIdx.x >> 6;
  const int g = blockIdx.x * 4 + wid;
  const int s = g & 2047, h = (g >> 11) & 7, b = g >> 14;
  const int token = b * SEQ + s;

  const bf16* qv = qvb + (long)token * qvStride + h * 32;
  const float* wrow = Wkv + lane * 32;
  float wq = 0.f, cb = 0.f;
#pragma unroll 8
  for (int q = 0; q < 32; q++) {
    const float qf = (float)qv[q];
    wq += wrow[q] * qf;
    cb += bkv[q] * qf;
  }

  const bf16* orow = outbuf + b * strideB + ((long)(h << 11) + s) * 512;
  float of[8], lg[8];
#pragma unroll
  for (int r = 0; r < 8; r++) {
    of[r] = (float)orow[r * 64 + lane];
    float p = of[r] * wq;
    for (int o = 1; o < 64; o <<= 1) p += __shfl_xor(p, o);
    lg[r] = p + cb;
  }
  float m = lg[0];
#pragma unroll
  for (int r = 1; r < 8; r++) m = fmaxf(m, lg[r]);
  float e[8], sum = 0.f;
#pragma unroll
  for (int r = 0; r < 8; r++) { e[r] = __expf(lg[r] - m); sum += e[r]; }
  const float inv = 1.f / sum;
  float o = 0.f;
#pragma unroll
  for (int r = 0; r < 8; r++) o += e[r] * inv * of[r];
  attn[(long)token * 512 + h * 64 + lane] = (bf16)o;
}

// ---------------------------------------------------------------------------
// LayerNorm over D=512 per token; optional split-K partial at +part2 elems.
// ---------------------------------------------------------------------------
__global__ __launch_bounds__(256)
void ln_kernel(const float* __restrict__ a, long part2,
               const float* __restrict__ bres, int bresT,
               const float* __restrict__ g, const float* __restrict__ be,
               float* __restrict__ outF, bf16* __restrict__ outB, int outT) {
  __shared__ float red[8];
  const int t = blockIdx.x, tid = threadIdx.x;
  const int b = t >> 11, s = t & 2047;
  const long ti = (long)t * 512;
  const long xi = (long)(s * BAT + b) * 512;
  const long ri = bresT ? xi : ti;
  float v0 = a[ti + tid]       + bres[ri + tid];
  float v1 = a[ti + 256 + tid] + bres[ri + 256 + tid];
  if (part2) { v0 += a[part2 + ti + tid]; v1 += a[part2 + ti + 256 + tid]; }
  float sum = v0 + v1, sq = v0 * v0 + v1 * v1;
  const int lane = tid & 63, wid = tid >> 6;
  for (int o = 1; o < 64; o <<= 1) { sum += __shfl_xor(sum, o); sq += __shfl_xor(sq, o); }
  if (lane == 0) { red[wid] = sum; red[4 + wid] = sq; }
  __syncthreads();
  sum = red[0] + red[1] + red[2] + red[3];
  sq  = red[4] + red[5] + red[6] + red[7];
  const float mu = sum * (1.f / 512.f);
  const float var = sq * (1.f / 512.f) - mu * mu;
  const float rs = rsqrtf(var + 1e-5f);
  const float y0 = (v0 - mu) * rs * g[tid] + be[tid];
  const float y1 = (v1 - mu) * rs * g[tid + 256] + be[tid + 256];
  const long oi = outT ? xi : ti;
  if (outF) { outF[oi + tid] = y0; outF[oi + 256 + tid] = y1; }
  if (outB) { outB[ti + tid] = (bf16)y0; outB[ti + 256 + tid] = (bf16)y1; }
}

// ---------------------------------------------------------------------------
extern "C" void kernel_launch(void* const* d_in, const int* in_sizes, int n_in,
                              void* d_out, int out_size, void* d_ws, size_t ws_size,
                              hipStream_t stream) {
  const float* x   = (const float*)d_in[0];
  const float* Wq  = (const float*)d_in[1];
  const float* bq  = (const float*)d_in[2];
  const float* Wk  = (const float*)d_in[3];
  const float* bk  = (const float*)d_in[4];
  const float* Wv  = (const float*)d_in[5];
  const float* bv  = (const float*)d_in[6];
  const float* Wqv = (const float*)d_in[7];
  const float* bqv = (const float*)d_in[8];
  const float* Wkv = (const float*)d_in[9];
  const float* bkv = (const float*)d_in[10];
  const float* Wf  = (const float*)d_in[11];
  const float* bfc = (const float*)d_in[12];
  const float* W1  = (const float*)d_in[13];
  const float* b1  = (const float*)d_in[14];
  const float* W2  = (const float*)d_in[15];
  const float* b2  = (const float*)d_in[16];
  const float* g1  = (const float*)d_in[17];
  const float* be1 = (const float*)d_in[18];
  const float* g2  = (const float*)d_in[19];
  const float* be2 = (const float*)d_in[20];

  char* ws = (char*)d_ws;
  size_t off = 0;
  auto alloc = [&](size_t bytes) -> void* {
    void* p = ws + off;
    off += (bytes + 1023) & ~(size_t)1023;
    return p;
  };
  // ---- persistent (~50 MB) ----
  bf16*  qkv   = (bf16*)alloc((size_t)NTOK * QKVW * 2);
  bf16*  vT    = (bf16*)alloc((size_t)BAT * 512 * SEQ * 2);
  bf16*  wtPk  = (bf16*)alloc((size_t)QKVW * 512 * 2);
  bf16*  WfT   = (bf16*)alloc(512 * 512 * 2);
  bf16*  W1T   = (bf16*)alloc((size_t)2048 * 512 * 2);
  bf16*  W2T   = (bf16*)alloc((size_t)512 * 2048 * 2);
  float* bcat  = (float*)alloc(QKVW * 4);
  bf16*  attn  = (bf16*)alloc((size_t)NTOK * 512 * 2);

  // ---- shared region (96 MB), phases temporally disjoint ----
  // attn phase: [outb 64]    ffn phase: [xb 8 | wfoP 32 | ln1f 16 | ln1b 8 | ffn1 32]
  char* reg = ws + off;
  bf16*  outb  = (bf16*)reg;                 //  0..64 (dead after stage2)
  bf16*  xb    = (bf16*)reg;                 //  0..8  (dead after projection)
  float* wfoP  = (float*)(reg + 8 * MB);     //  8..40 (2 f32 partials)
  float* ln1f  = (float*)(reg + 40 * MB);    // 40..56
  bf16*  ln1b  = (bf16*)(reg + 56 * MB);     // 56..64
  bf16*  ffn1  = (bf16*)(reg + 64 * MB);     // 64..96

  const dim3 tb(32, 8);
  // q scale folds softmax's 1/sqrt(64) AND log2(e) so attn can use exp2
  transpose_w_kernel<<<dim3(16, 16), tb, 0, stream>>>(Wq,  wtPk,              512, 512, 0.18033688011112042f);
  transpose_w_kernel<<<dim3(16, 16), tb, 0, stream>>>(Wk,  wtPk + 512  * 512, 512, 512, 1.f);
  transpose_w_kernel<<<dim3(16, 16), tb, 0, stream>>>(Wv,  wtPk + 1024 * 512, 512, 512, 1.f);
  transpose_w_kernel<<<dim3(8, 16),  tb, 0, stream>>>(Wqv, wtPk + 1536 * 512, 512, 256, 0.17677669529663687f);
  transpose_w_kernel<<<dim3(16, 16), tb, 0, stream>>>(Wf,  WfT, 512, 512, 1.f);
  transpose_w_kernel<<<dim3(64, 16), tb, 0, stream>>>(W1,  W1T, 512, 2048, 1.f);
  transpose_w_kernel<<<dim3(16, 64), tb, 0, stream>>>(W2,  W2T, 2048, 512, 1.f);
  build_bias_kernel<<<7, 256, 0, stream>>>(bq, bk, bv, bqv, bcat);
  convert_x_kernel<<<2048, 256, 0, stream>>>(x, xb);

  // fused q|k|v|qv projection: [8192,512] @ [1792,512]^T -> [8192,1792]
  gemm_bt<<<dim3(14, 64, 1), 256, 0, stream>>>(xb, wtPk, qkv, bcat,
      512, 512, 512, QKVW, 0, 0, 0, 1.f, 1);

  transpose_v_kernel<<<dim3(64, 16, 4), tb, 0, stream>>>(qkv, vT);

  // fused attention: score+softmax+PV; V-cols split across z (2 blocks/CU)
  attn_kernel<<<dim3(SEQ / 64, NH, BAT * 2), 512, 0, stream>>>(qkv, vT, outb);

  stage2_kernel<<<BAT * NH * SEQ / 4, 256, 0, stream>>>(outb, (long)NH * SEQ * 512,
      qkv + 1536, QKVW, Wkv, bkv, attn);

  const long sWf = (long)NTOK * 512;
  // Wf projection, split-K z=2, f32 partials (bias on z==0), summed by ln1
  gemm_bt<<<dim3(4, 64, 2), 256, 0, stream>>>(attn, WfT, wfoP, bfc,
      256, 512, 512, 512, 256, 256, sWf, 1.f, 0);
  ln_kernel<<<NTOK, 256, 0, stream>>>(wfoP, sWf, x, 1, g1, be1, ln1f, ln1b, 0);
  gemm_bt<<<dim3(16, 64, 1), 256, 0, stream>>>(ln1b, W1T, ffn1, b1,
      512, 512, 512, 2048, 0, 0, 0, 1.f, 1 | 2);
  // ffn2, split-K z=2, f32 partials (bias on z==0), summed by ln2
  gemm_bt<<<dim3(4, 64, 2), 256, 0, stream>>>(ffn1, W2T, wfoP, b2,
      1024, 2048, 2048, 512, 1024, 1024, sWf, 1.f, 0);
  ln_kernel<<<NTOK, 256, 0, stream>>>(wfoP, sWf, ln1f, 0, g2, be2, (float*)d_out, nullptr, 1);
}

// Round 19
// 467.998 us; speedup vs baseline: 1.2327x; 1.0979x over previous
//
#include <hip/hip_runtime.h>
#include <hip/hip_bf16.h>

typedef __bf16 bf16;
typedef bf16 bf16x4 __attribute__((ext_vector_type(4)));
typedef bf16 bf16x8 __attribute__((ext_vector_type(8)));
typedef float f32x4 __attribute__((ext_vector_type(4)));

constexpr int SEQ  = 2048;
constexpr int BAT  = 4;
constexpr int NH   = 8;
constexpr int NTOK = SEQ * BAT;   // 8192
constexpr int QKVW = 1792;        // fused projection width: 512+512+512+256
constexpr size_t MB = 1ull << 20;

// ---------------------------------------------------------------------------
// async global->LDS 16B copy (wave-uniform LDS base + lane*16, m104)
// ---------------------------------------------------------------------------
__device__ inline void async_lds16(const void* g, void* l) {
  __builtin_amdgcn_global_load_lds(
      (__attribute__((address_space(1))) void*)(g),
      (__attribute__((address_space(3))) void*)(l), 16, 0, 0);
}

#define MFMA16 __builtin_amdgcn_mfma_f32_16x16x32_bf16

// ---------------------------------------------------------------------------
// Fused attention + stage-2 composition (round-19 = round-18 with the LDS
// pointer-array aggregate initializers replaced by scalar pointers; arrays
// of addrspacecast'd LDS pointers fail to compile on gfx950).
// KV loop = round-11 structure verbatim (KVBLK=256, 297 us proven).
// Epilogue fuses stage-2; outb buffer + stage2 kernel eliminated.
// ---------------------------------------------------------------------------
__global__ __launch_bounds__(512)
void attn_kernel(const bf16* __restrict__ qkv, const bf16* __restrict__ vT,
                 const float* __restrict__ Wkv, const float* __restrict__ bkv,
                 bf16* __restrict__ attnOut) {
  __shared__ __align__(16) char MAIN[8192 + 2 * 32768 + 2 * 16384]; // 106.5 KB
  bf16* Qs  = (bf16*)MAIN;
  bf16* Ks0 = (bf16*)(MAIN + 8192);
  bf16* Ks1 = (bf16*)(MAIN + 8192 + 32768);
  bf16* Ps0 = (bf16*)(MAIN + 73728);
  bf16* Ps1 = (bf16*)(MAIN + 73728 + 16384);
  __shared__ float rsAll[8][64];
  __shared__ float rsInv[64];
  __shared__ float cbL[64];
  __shared__ float lgL[8][64];
  __shared__ float cpL[8][64];

  const int tid = threadIdx.x;
  const int lane = tid & 63, w = tid >> 6;
  const int r16 = lane & 15, rq = lane >> 4;
  const int qb = blockIdx.x, h = blockIdx.y, b = blockIdx.z;

  // ---- stage Q tile [64 rows][64 d] (head h = q cols h*64..) ----
  const bf16* qbase = qkv + ((long)b * SEQ + qb * 64) * QKVW + h * 64;
  {
    const int rr = tid >> 3, sl = tid & 7;
    async_lds16(qbase + (long)rr * QKVW + ((sl ^ (rr & 7)) << 3),
                Qs + (size_t)w * 512);                 // wave-uniform base
  }
  // ---- K staging [256 rows][64 d], 4 chunks/thread ----
  const bf16* kbase = qkv + (long)b * SEQ * QKVW + 512 + h * 64;
  auto stageK = [&](bf16* dst, int t0) {
#pragma unroll
    for (int g = 0; g < 4; g++) {
      const int c = g * 512 + tid;                   // lane-contiguous
      const int rr = c >> 3, sl = c & 7;
      async_lds16(kbase + (long)(t0 + rr) * QKVW + ((sl ^ (rr & 7)) << 3),
                  dst + (size_t)(g * 8 + w) * 512);
    }
  };
  // per-lane V row pointers (vT: [B][512 cols][SEQ])
  const bf16* vp[4];
#pragma unroll
  for (int n = 0; n < 4; n++)
    vp[n] = vT + ((long)b * 512 + w * 64 + n * 16 + r16) * SEQ + rq * 8;

  f32x4 acc[4][4] = {};   // [m-frag][n-frag]
  float rs[4] = {};       // row-sum partials (per j)

  stageK(Ks0, 0);
  asm volatile("s_waitcnt vmcnt(0)" ::: "memory");
  __builtin_amdgcn_s_barrier();
  __builtin_amdgcn_sched_barrier(0);

  // Q b-frags held in regs for whole kernel
  bf16x8 qf[4][2];
#pragma unroll
  for (int j = 0; j < 4; j++)
#pragma unroll
    for (int kf = 0; kf < 2; kf++) {
      const int row = j * 16 + r16;
      qf[j][kf] = *(const bf16x8*)&Qs[row * 64 + (((kf * 4 + rq) ^ (row & 7)) << 3)];
    }

  const int krow = w * 16 + r16;              // key row within a 128-half
  for (int t = 0; t < 8; ++t) {
    const int t0 = t * 256;
    const bf16* Kc = (t & 1) ? Ks1 : Ks0;     // current K buffer
    bf16* Kn = (t & 1) ? Ks0 : Ks1;           // next K buffer
    if (t) {
      asm volatile("s_waitcnt vmcnt(0)" ::: "memory");   // K(t) DMA resident
      __builtin_amdgcn_s_barrier();
      __builtin_amdgcn_sched_barrier(0);
    }
    if (t < 7) stageK(Kn, t0 + 256);                     // K(t+1): full-step lead
    // V group 0 preload (consumed in PV g=0)
    bf16x8 vcur[4];
#pragma unroll
    for (int n = 0; n < 4; n++)
      vcur[n] = *(const bf16x8*)(vp[n] + t0);
    // ---- QK^T both halves (swapped: S^T[key][qrow]) ----
    bf16x8 kfa[2], kfb[2];
#pragma unroll
    for (int kf = 0; kf < 2; kf++) {
      const int so = (((kf * 4 + rq) ^ (krow & 7)) << 3);
      kfa[kf] = *(const bf16x8*)&Kc[krow * 64 + so];
      kfb[kf] = *(const bf16x8*)&Kc[(128 + krow) * 64 + so];
    }
    f32x4 sA[4] = {}, sB[4] = {};
#pragma unroll
    for (int j = 0; j < 4; j++) {
      sA[j] = MFMA16(kfa[0], qf[j][0], sA[j], 0, 0, 0);
      sA[j] = MFMA16(kfa[1], qf[j][1], sA[j], 0, 0, 0);
      sB[j] = MFMA16(kfb[0], qf[j][0], sB[j], 0, 0, 0);
      sB[j] = MFMA16(kfb[1], qf[j][1], sB[j], 0, 0, 0);
    }
    // ---- exp2 + row-sum + pack P (both halves; base-2 logits, scale folded) ----
#pragma unroll
    for (int half = 0; half < 2; half++) {
      bf16* Pcur = half ? Ps1 : Ps0;
#pragma unroll
      for (int j = 0; j < 4; j++) {
        const f32x4 sv = half ? sB[j] : sA[j];
        const float e0 = exp2f(sv[0]), e1 = exp2f(sv[1]);
        const float e2 = exp2f(sv[2]), e3 = exp2f(sv[3]);
        rs[j] += (e0 + e1) + (e2 + e3);
        bf16x4 pk; pk[0] = (bf16)e0; pk[1] = (bf16)e1; pk[2] = (bf16)e2; pk[3] = (bf16)e3;
        const int row = j * 16 + r16;
        *(bf16x4*)&Pcur[row * 128 + (((w * 2 + (rq >> 1)) ^ (row & 7)) << 3) + ((rq & 1) << 2)] = pk;
      }
    }
    asm volatile("s_waitcnt lgkmcnt(0)" ::: "memory");   // P writes drained
    __builtin_amdgcn_s_barrier();
    __builtin_amdgcn_sched_barrier(0);
    // ---- PV: acc += P[64 x 256] @ V[256 x 64(wave)], 8 rolling groups ----
#pragma unroll
    for (int g = 0; g < 8; g++) {
      const bf16* Ph = (g >> 2) ? Ps1 : Ps0;
      const int c = g & 3;
      bf16x8 vnxt[4];
      if (g < 7) {
#pragma unroll
        for (int n = 0; n < 4; n++)
          vnxt[n] = *(const bf16x8*)(vp[n] + t0 + (g + 1) * 32);
      }
      bf16x8 pf[4];
#pragma unroll
      for (int i = 0; i < 4; i++) {
        const int row = i * 16 + r16;
        pf[i] = *(const bf16x8*)&Ph[row * 128 + (((rq + c * 4) ^ (row & 7)) << 3)];
      }
      __builtin_amdgcn_s_setprio(1);
#pragma unroll
      for (int i = 0; i < 4; i++) {
        acc[i][0] = MFMA16(pf[i], vcur[0], acc[i][0], 0, 0, 0);
        acc[i][1] = MFMA16(pf[i], vcur[1], acc[i][1], 0, 0, 0);
        acc[i][2] = MFMA16(pf[i], vcur[2], acc[i][2], 0, 0, 0);
        acc[i][3] = MFMA16(pf[i], vcur[3], acc[i][3], 0, 0, 0);
      }
      __builtin_amdgcn_s_setprio(0);
#pragma unroll
      for (int n = 0; n < 4; n++) vcur[n] = vnxt[n];     // renamed by unroll
    }
    __builtin_amdgcn_s_barrier();          // P consumed -> next write safe
  }

  // ---- row-sum reduce -> rsInv ----
#pragma unroll
  for (int j = 0; j < 4; j++) {
    rs[j] += __shfl_xor(rs[j], 16);
    rs[j] += __shfl_xor(rs[j], 32);
  }
  if (rq == 0) {
#pragma unroll
    for (int j = 0; j < 4; j++) rsAll[w][j * 16 + r16] = rs[j];
  }
  __syncthreads();
  if (tid < 64) {
    float tot = 0.f;
#pragma unroll
    for (int u = 0; u < 8; u++) tot += rsAll[u][tid];
    rsInv[tid] = 1.f / tot;
  }
  __syncthreads();                          // Ks/Ps dead beyond this point

  // ================= fused stage-2 composition =================
  bf16*  qvL   = (bf16*)MAIN;               // [64][32] bf16 (aliases Qs, dead)
  float* WkvL  = (float*)(MAIN + 8192);     // [64][32] f32
  float* wqL   = (float*)(MAIN + 16384);    // [64][64] f32
  bf16*  slab  = (bf16*)(MAIN + 32768);     // 8 x [64][64] bf16

  // load qv tile + Wkv
  {
    const int qrow = tid >> 3, q0 = (tid & 7) * 4;
    *(bf16x4*)&qvL[qrow * 32 + q0] =
        *(const bf16x4*)(qkv + ((long)(b * SEQ + qb * 64 + qrow)) * QKVW + 1536 + h * 32 + q0);
    *(float4*)&WkvL[tid * 4] = *(const float4*)&Wkv[tid * 4];
  }
  __syncthreads();
  // wq[qrow][hd] = sum_q Wkv[hd][q] * qv[qrow][q];  cb[qrow] = sum_q bkv[q]*qv
  {
    const int qrow = tid & 63, hd0 = (tid >> 6) * 8;
    float s[8] = {};
#pragma unroll 4
    for (int q = 0; q < 32; q++) {
      const float qf = (float)qvL[qrow * 32 + q];
#pragma unroll
      for (int d = 0; d < 8; d++) s[d] += WkvL[(hd0 + d) * 32 + q] * qf;
    }
#pragma unroll
    for (int d = 0; d < 8; d++) wqL[qrow * 64 + hd0 + d] = s[d];
    if (tid < 64) {
      float cs = 0.f;
      for (int q = 0; q < 32; q++) cs += bkv[q] * (float)qvL[tid * 32 + q];
      cbL[tid] = cs;
    }
  }
  __syncthreads();
  // logit for rule w: in-register dot + 16-lane shfl reduce
#pragma unroll
  for (int i = 0; i < 4; i++) {
#pragma unroll
    for (int rg = 0; rg < 4; rg++) {
      const int qrow = i * 16 + rq * 4 + rg;
      float p = 0.f;
#pragma unroll
      for (int n = 0; n < 4; n++)
        p += acc[i][n][rg] * wqL[qrow * 64 + n * 16 + r16];
      p *= rsInv[qrow];
      p += __shfl_xor(p, 1); p += __shfl_xor(p, 2);
      p += __shfl_xor(p, 4); p += __shfl_xor(p, 8);
      if (r16 == 0) lgL[w][qrow] = p + cbL[qrow];
    }
  }
  __syncthreads();
  // composition softmax over rules (natural exp; qv pre-scaled 1/sqrt(32))
  if (tid < 64) {
    float l[8];
#pragma unroll
    for (int r = 0; r < 8; r++) l[r] = lgL[r][tid];
    float m = l[0];
#pragma unroll
    for (int r = 1; r < 8; r++) m = fmaxf(m, l[r]);
    float e[8], sum = 0.f;
#pragma unroll
    for (int r = 0; r < 8; r++) { e[r] = __expf(l[r] - m); sum += e[r]; }
    const float inv = 1.f / sum;
#pragma unroll
    for (int r = 0; r < 8; r++) cpL[r][tid] = e[r] * inv;
  }
  __syncthreads();
  // comp-weighted slab write (wave w -> slab w)
  {
    bf16* ms = slab + w * 4096;
#pragma unroll
    for (int i = 0; i < 4; i++) {
#pragma unroll
      for (int rg = 0; rg < 4; rg++) {
        const int qrow = i * 16 + rq * 4 + rg;
        const float cw = cpL[w][qrow] * rsInv[qrow];
#pragma unroll
        for (int n = 0; n < 4; n++)
          ms[qrow * 64 + n * 16 + r16] = (bf16)(acc[i][n][rg] * cw);
      }
    }
  }
  __syncthreads();
  // 8-way slab sum + store attn[token][h*64+hd]
  {
    const int qrow = tid >> 3, hd0 = (tid & 7) * 8;
    float o[8] = {};
#pragma unroll
    for (int r = 0; r < 8; r++) {
      const bf16x8 v = *(const bf16x8*)&slab[r * 4096 + qrow * 64 + hd0];
#pragma unroll
      for (int e = 0; e < 8; e++) o[e] += (float)v[e];
    }
    bf16x8 ov;
#pragma unroll
    for (int e = 0; e < 8; e++) ov[e] = (bf16)o[e];
    *(bf16x8*)&attnOut[((long)(b * SEQ + qb * 64 + qrow)) * 512 + h * 64 + hd0] = ov;
  }
}

// ---------------------------------------------------------------------------
// bf16 MFMA GEMM, 128x128 tile, BK=32, 4 waves, 3-deep counted-vmcnt pipeline
// (T3+T4) + T1 XCD-chunked block swizzle + T5 setprio.  [round-4 proven loop]
// bias applied only on the z==0 slice. flags: bit0 = bf16 out, bit1 = relu.
// Split-K: sAz/sBz = per-z K-offsets (elements), sCz = partial-buffer stride.
// ---------------------------------------------------------------------------
__global__ __launch_bounds__(256)
void gemm_bt(const bf16* __restrict__ A, const bf16* __restrict__ B,
             void* __restrict__ C, const float* __restrict__ bias,
             int K, int lda, int ldb, int ldc,
             long sAz, long sBz, long sCz,
             float scale, int flags) {
  constexpr int LPT = 4;
  __shared__ __align__(16) bf16 As[3][128 * 32];
  __shared__ __align__(16) bf16 Bs[3][128 * 32];

  const int tid  = threadIdx.x;
  const int lane = tid & 63;
  const int w    = tid >> 6;
  const int wr   = w >> 1, wc = w & 1;

  const int gx = gridDim.x, gy = gridDim.y;
  const int nwg = gx * gy * gridDim.z;
  const int flat = blockIdx.x + gx * (blockIdx.y + gy * blockIdx.z);
  const int q = nwg >> 3, r = nwg & 7;
  const int xcd = flat & 7, pos = flat >> 3;
  int swz = (xcd < r ? xcd * (q + 1) : r * (q + 1) + (xcd - r) * q) + pos;
  const int bx = swz % gx; swz /= gx;
  const int by = swz % gy;
  const long z = swz / gy;

  const bf16* Ab = A + (long)by * 128 * lda + z * sAz;
  const bf16* Bb = B + (long)bx * 128 * ldb + z * sBz;

  const bf16* aSrc[2];
  const bf16* bSrc[2];
#pragma unroll
  for (int g = 0; g < 2; g++) {
    const int c = (w * 2 + g) * 64 + lane;
    const int rr = c >> 2, sl = c & 3;
    aSrc[g] = Ab + (long)rr * lda + ((sl ^ ((rr >> 1) & 3)) << 3);
    bSrc[g] = Bb + (long)rr * ldb + ((sl ^ ((rr >> 1) & 3)) << 3);
  }

  f32x4 acc[4][4] = {};
  const int r16 = lane & 15, kq = lane >> 4;
  const int so = ((kq ^ ((r16 >> 1) & 3)) << 3);

  auto stage = [&](int buf, int k0) {
#pragma unroll
    for (int g = 0; g < 2; g++)
      async_lds16(aSrc[g] + k0, &As[buf][(w * 2 + g) * 512]);
#pragma unroll
    for (int g = 0; g < 2; g++)
      async_lds16(bSrc[g] + k0, &Bs[buf][(w * 2 + g) * 512]);
  };
  bf16x8 areg[4], breg[4];
  auto loadfrags = [&](int buf) {
#pragma unroll
    for (int i = 0; i < 4; i++)
      areg[i] = *(const bf16x8*)&As[buf][(wr * 64 + i * 16 + r16) * 32 + so];
#pragma unroll
    for (int j = 0; j < 4; j++)
      breg[j] = *(const bf16x8*)&Bs[buf][(wc * 64 + j * 16 + r16) * 32 + so];
  };
  auto domfma = [&]() {
    __builtin_amdgcn_s_setprio(1);
#pragma unroll
    for (int i = 0; i < 4; i++)
#pragma unroll
      for (int j = 0; j < 4; j++)
        acc[i][j] = MFMA16(areg[i], breg[j], acc[i][j], 0, 0, 0);
    __builtin_amdgcn_s_setprio(0);
  };

  const int nt = K >> 5;
  stage(0, 0);
  if (nt > 1) stage(1, 32);

  int cs = 2, cc = 0;
  for (int t = 0; t + 2 < nt; ++t) {
    stage(cs, (t + 2) * 32);
    asm volatile("s_waitcnt vmcnt(%0)" : : "n"(2 * LPT) : "memory");
    __builtin_amdgcn_s_barrier();
    loadfrags(cc);
    asm volatile("s_waitcnt lgkmcnt(0)" : : : "memory");
    __builtin_amdgcn_sched_barrier(0);
    __builtin_amdgcn_s_barrier();
    domfma();
    if (++cs == 3) cs = 0;
    if (++cc == 3) cc = 0;
  }
  if (nt >= 2) {
    asm volatile("s_waitcnt vmcnt(%0)" : : "n"(LPT) : "memory");
    __builtin_amdgcn_s_barrier();
    loadfrags(cc);
    asm volatile("s_waitcnt lgkmcnt(0)" : : : "memory");
    __builtin_amdgcn_sched_barrier(0);
    domfma();
    if (++cc == 3) cc = 0;
  }
  asm volatile("s_waitcnt vmcnt(0)" : : : "memory");
  __builtin_amdgcn_s_barrier();
  loadfrags(cc);
  domfma();

  const long rowBase = (long)by * 128 + wr * 64;
  const int  colBase = bx * 128 + wc * 64;
  float* Cf = (float*)C;
  bf16*  Cb = (bf16*)C;
  const int rq = lane >> 4;
#pragma unroll
  for (int i = 0; i < 4; i++) {
#pragma unroll
    for (int j = 0; j < 4; j++) {
      const int col = colBase + j * 16 + r16;
      const float bv = (bias && z == 0) ? bias[col] : 0.f;
#pragma unroll
      for (int rg = 0; rg < 4; rg++) {
        const long row = rowBase + i * 16 + rq * 4 + rg;
        float y = (acc[i][j][rg] + bv) * scale;
        if (flags & 2) y = fmaxf(y, 0.f);
        const long idx = z * sCz + row * (long)ldc + col;
        if (flags & 1) Cb[idx] = (bf16)y;
        else           Cf[idx] = y;
      }
    }
  }
}

// ---------------------------------------------------------------------------
__global__ void transpose_w_kernel(const float* __restrict__ in, bf16* __restrict__ out,
                                   int K, int N, float scale) {
  __shared__ float t[32][33];
  const int n0 = blockIdx.x * 32, k0 = blockIdx.y * 32;
  const int tx = threadIdx.x, ty = threadIdx.y;
#pragma unroll
  for (int i = ty; i < 32; i += 8)
    t[i][tx] = in[(long)(k0 + i) * N + n0 + tx];
  __syncthreads();
#pragma unroll
  for (int i = ty; i < 32; i += 8)
    out[(long)(n0 + i) * K + k0 + tx] = (bf16)(t[tx][i] * scale);
}

__global__ void build_bias_kernel(const float* bq, const float* bk,
                                  const float* bv, const float* bqv,
                                  float* __restrict__ out) {
  const int i = blockIdx.x * 256 + threadIdx.x;
  float v;
  if (i < 512)       v = bq[i] * 0.18033688011112042f;   // 0.125 * log2(e)
  else if (i < 1024) v = bk[i - 512];
  else if (i < 1536) v = bv[i - 1024];
  else               v = bqv[i - 1536] * 0.17677669529663687f;
  out[i] = v;
}

// v (cols 1024..1535 of qkv) -> vT bf16 [B][512][S]
__global__ void transpose_v_kernel(const bf16* __restrict__ qkv, bf16* __restrict__ vT) {
  __shared__ bf16 t[32][33];
  const int s0 = blockIdx.x * 32, c0 = blockIdx.y * 32, b = blockIdx.z;
  const int tx = threadIdx.x, ty = threadIdx.y;
#pragma unroll
  for (int i = ty; i < 32; i += 8)
    t[i][tx] = qkv[((long)b * SEQ + s0 + i) * QKVW + 1024 + c0 + tx];
  __syncthreads();
#pragma unroll
  for (int i = ty; i < 32; i += 8)
    vT[(long)b * 512 * SEQ + (long)(c0 + i) * SEQ + s0 + tx] = t[tx][i];
}

// x f32 [S][B][D] -> xb bf16 [B*S][D]
__global__ __launch_bounds__(256)
void convert_x_kernel(const float* __restrict__ x, bf16* __restrict__ xb) {
  const long i0 = ((long)blockIdx.x * 256 + threadIdx.x) * 8;
  const int t = (int)(i0 >> 9), d = (int)(i0 & 511);
  const int b = t >> 11, s = t & 2047;
  const float* src = x + ((long)(s * BAT + b) << 9) + d;
  const float4 f0 = *(const float4*)(src);
  const float4 f1 = *(const float4*)(src + 4);
  bf16x8 o;
  o[0] = (bf16)f0.x; o[1] = (bf16)f0.y; o[2] = (bf16)f0.z; o[3] = (bf16)f0.w;
  o[4] = (bf16)f1.x; o[5] = (bf16)f1.y; o[6] = (bf16)f1.z; o[7] = (bf16)f1.w;
  *(bf16x8*)&xb[i0] = o;
}

// ---------------------------------------------------------------------------
// LayerNorm over D=512 per token; optional split-K partial at +part2 elems.
// ---------------------------------------------------------------------------
__global__ __launch_bounds__(256)
void ln_kernel(const float* __restrict__ a, long part2,
               const float* __restrict__ bres, int bresT,
               const float* __restrict__ g, const float* __restrict__ be,
               float* __restrict__ outF, bf16* __restrict__ outB, int outT) {
  __shared__ float red[8];
  const int t = blockIdx.x, tid = threadIdx.x;
  const int b = t >> 11, s = t & 2047;
  const long ti = (long)t * 512;
  const long xi = (long)(s * BAT + b) * 512;
  const long ri = bresT ? xi : ti;
  float v0 = a[ti + tid]       + bres[ri + tid];
  float v1 = a[ti + 256 + tid] + bres[ri + 256 + tid];
  if (part2) { v0 += a[part2 + ti + tid]; v1 += a[part2 + ti + 256 + tid]; }
  float sum = v0 + v1, sq = v0 * v0 + v1 * v1;
  const int lane = tid & 63, wid = tid >> 6;
  for (int o = 1; o < 64; o <<= 1) { sum += __shfl_xor(sum, o); sq += __shfl_xor(sq, o); }
  if (lane == 0) { red[wid] = sum; red[4 + wid] = sq; }
  __syncthreads();
  sum = red[0] + red[1] + red[2] + red[3];
  sq  = red[4] + red[5] + red[6] + red[7];
  const float mu = sum * (1.f / 512.f);
  const float var = sq * (1.f / 512.f) - mu * mu;
  const float rs = rsqrtf(var + 1e-5f);
  const float y0 = (v0 - mu) * rs * g[tid] + be[tid];
  const float y1 = (v1 - mu) * rs * g[tid + 256] + be[tid + 256];
  const long oi = outT ? xi : ti;
  if (outF) { outF[oi + tid] = y0; outF[oi + 256 + tid] = y1; }
  if (outB) { outB[ti + tid] = (bf16)y0; outB[ti + 256 + tid] = (bf16)y1; }
}

// ---------------------------------------------------------------------------
extern "C" void kernel_launch(void* const* d_in, const int* in_sizes, int n_in,
                              void* d_out, int out_size, void* d_ws, size_t ws_size,
                              hipStream_t stream) {
  const float* x   = (const float*)d_in[0];
  const float* Wq  = (const float*)d_in[1];
  const float* bq  = (const float*)d_in[2];
  const float* Wk  = (const float*)d_in[3];
  const float* bk  = (const float*)d_in[4];
  const float* Wv  = (const float*)d_in[5];
  const float* bv  = (const float*)d_in[6];
  const float* Wqv = (const float*)d_in[7];
  const float* bqv = (const float*)d_in[8];
  const float* Wkv = (const float*)d_in[9];
  const float* bkv = (const float*)d_in[10];
  const float* Wf  = (const float*)d_in[11];
  const float* bfc = (const float*)d_in[12];
  const float* W1  = (const float*)d_in[13];
  const float* b1  = (const float*)d_in[14];
  const float* W2  = (const float*)d_in[15];
  const float* b2  = (const float*)d_in[16];
  const float* g1  = (const float*)d_in[17];
  const float* be1 = (const float*)d_in[18];
  const float* g2  = (const float*)d_in[19];
  const float* be2 = (const float*)d_in[20];

  char* ws = (char*)d_ws;
  size_t off = 0;
  auto alloc = [&](size_t bytes) -> void* {
    void* p = ws + off;
    off += (bytes + 1023) & ~(size_t)1023;
    return p;
  };
  // ---- persistent (~50 MB) ----
  bf16*  qkv   = (bf16*)alloc((size_t)NTOK * QKVW * 2);
  bf16*  vT    = (bf16*)alloc((size_t)BAT * 512 * SEQ * 2);
  bf16*  wtPk  = (bf16*)alloc((size_t)QKVW * 512 * 2);
  bf16*  WfT   = (bf16*)alloc(512 * 512 * 2);
  bf16*  W1T   = (bf16*)alloc((size_t)2048 * 512 * 2);
  bf16*  W2T   = (bf16*)alloc((size_t)512 * 2048 * 2);
  float* bcat  = (float*)alloc(QKVW * 4);
  bf16*  attn  = (bf16*)alloc((size_t)NTOK * 512 * 2);

  // ---- shared region, phases temporally disjoint ----
  // ffn phase: [xb 8 | wfoP 32 | ln1f 16 | ln1b 8 | ffn1 32]
  char* reg = ws + off;
  bf16*  xb    = (bf16*)reg;                 //  0..8  (dead after projection)
  float* wfoP  = (float*)(reg + 8 * MB);     //  8..40 (2 f32 partials)
  float* ln1f  = (float*)(reg + 40 * MB);    // 40..56
  bf16*  ln1b  = (bf16*)(reg + 56 * MB);     // 56..64
  bf16*  ffn1  = (bf16*)(reg + 64 * MB);     // 64..96

  const dim3 tb(32, 8);
  // q scale folds softmax's 1/sqrt(64) AND log2(e) so attn can use exp2
  transpose_w_kernel<<<dim3(16, 16), tb, 0, stream>>>(Wq,  wtPk,              512, 512, 0.18033688011112042f);
  transpose_w_kernel<<<dim3(16, 16), tb, 0, stream>>>(Wk,  wtPk + 512  * 512, 512, 512, 1.f);
  transpose_w_kernel<<<dim3(16, 16), tb, 0, stream>>>(Wv,  wtPk + 1024 * 512, 512, 512, 1.f);
  transpose_w_kernel<<<dim3(8, 16),  tb, 0, stream>>>(Wqv, wtPk + 1536 * 512, 512, 256, 0.17677669529663687f);
  transpose_w_kernel<<<dim3(16, 16), tb, 0, stream>>>(Wf,  WfT, 512, 512, 1.f);
  transpose_w_kernel<<<dim3(64, 16), tb, 0, stream>>>(W1,  W1T, 512, 2048, 1.f);
  transpose_w_kernel<<<dim3(16, 64), tb, 0, stream>>>(W2,  W2T, 2048, 512, 1.f);
  build_bias_kernel<<<7, 256, 0, stream>>>(bq, bk, bv, bqv, bcat);
  convert_x_kernel<<<2048, 256, 0, stream>>>(x, xb);

  // fused q|k|v|qv projection: [8192,512] @ [1792,512]^T -> [8192,1792]
  gemm_bt<<<dim3(14, 64, 1), 256, 0, stream>>>(xb, wtPk, qkv, bcat,
      512, 512, 512, QKVW, 0, 0, 0, 1.f, 1);

  transpose_v_kernel<<<dim3(64, 16, 4), tb, 0, stream>>>(qkv, vT);

  // fused attention + stage-2: writes attn[] directly (no outb round-trip)
  attn_kernel<<<dim3(SEQ / 64, NH, BAT), 512, 0, stream>>>(qkv, vT, Wkv, bkv, attn);

  const long sWf = (long)NTOK * 512;
  // Wf projection, split-K z=2, f32 partials (bias on z==0), summed by ln1
  gemm_bt<<<dim3(4, 64, 2), 256, 0, stream>>>(attn, WfT, wfoP, bfc,
      256, 512, 512, 512, 256, 256, sWf, 1.f, 0);
  ln_kernel<<<NTOK, 256, 0, stream>>>(wfoP, sWf, x, 1, g1, be1, ln1f, ln1b, 0);
  gemm_bt<<<dim3(16, 64, 1), 256, 0, stream>>>(ln1b, W1T, ffn1, b1,
      512, 512, 512, 2048, 0, 0, 0, 1.f, 1 | 2);
  // ffn2, split-K z=2, f32 partials (bias on z==0), summed by ln2
  gemm_bt<<<dim3(4, 64, 2), 256, 0, stream>>>(ffn1, W2T, wfoP, b2,
      1024, 2048, 2048, 512, 1024, 1024, sWf, 1.f, 0);
  ln_kernel<<<NTOK, 256, 0, stream>>>(wfoP, sWf, ln1f, 0, g2, be2, (float*)d_out, nullptr, 1);
}